// Round 2
// baseline (831.049 us; speedup 1.0000x reference)
//
#include <hip/hip_runtime.h>
#include <math.h>

#define B_  8
#define H_  8
#define C_  512
#define L_  1024
#define DH  64
#define WIN 4

// ---------------------------------------------------------------------------
// Batched GEMM: Y[b] = (W @ Xin[b] + bias) * scale
//   W: (C,C) row-major, Xin per MODE, Y: (B,C,L)
//   MODE 0: X is (B,C,L)
//   MODE 1: X is attention output in (B,H,L,Dh); logical X[c][l] = X[b][c/64][l][c%64]
// Block: 256 threads, 64x64 output tile, 4x4 micro-tile, K-step 16.
// ---------------------------------------------------------------------------
template <int MODE>
__global__ __launch_bounds__(256) void gemm_kernel(
    const float* __restrict__ W, const float* __restrict__ bias,
    const float* __restrict__ X, float* __restrict__ Y, float scale)
{
    __shared__ float As[16][68];  // As[c'][o']
    __shared__ float Bs[16][68];  // Bs[c'][l']

    const int b     = blockIdx.z;
    const int oBase = blockIdx.y * 64;
    const int lBase = blockIdx.x * 64;
    const int t  = threadIdx.x;
    const int tx = t & 15;   // l direction
    const int ty = t >> 4;   // o direction

    float acc[4][4] = {};
    const float* Xb = X + (size_t)b * C_ * L_;

    for (int c0 = 0; c0 < C_; c0 += 16) {
        // stage W tile (64 o x 16 c), transposed into As[c'][o']
        {
            const int cc = t & 15, oo = t >> 4;
#pragma unroll
            for (int p = 0; p < 4; ++p)
                As[cc][oo + 16 * p] = W[(size_t)(oBase + oo + 16 * p) * C_ + c0 + cc];
        }
        // stage X tile (16 c x 64 l) into Bs[c'][l']
        if (MODE == 0) {
            const int ll = t & 63, cc = t >> 6;
#pragma unroll
            for (int p = 0; p < 4; ++p)
                Bs[cc + 4 * p][ll] = Xb[(size_t)(c0 + cc + 4 * p) * L_ + lBase + ll];
        } else {
            const int cc = t & 15, l0 = t >> 4;
            const int c = c0 + cc;
            const int h = c >> 6, d = c & 63;
#pragma unroll
            for (int p = 0; p < 4; ++p) {
                const int ll = l0 + 16 * p;
                Bs[cc][ll] = X[(((size_t)b * H_ + h) * L_ + lBase + ll) * DH + d];
            }
        }
        __syncthreads();
#pragma unroll
        for (int k = 0; k < 16; ++k) {
            float a[4], bb[4];
#pragma unroll
            for (int i = 0; i < 4; ++i) a[i] = As[k][ty + 16 * i];
#pragma unroll
            for (int j = 0; j < 4; ++j) bb[j] = Bs[k][tx + 16 * j];
#pragma unroll
            for (int i = 0; i < 4; ++i)
#pragma unroll
                for (int j = 0; j < 4; ++j) acc[i][j] += a[i] * bb[j];
        }
        __syncthreads();
    }

    float* Yb = Y + (size_t)b * C_ * L_;
#pragma unroll
    for (int i = 0; i < 4; ++i) {
        const int o  = oBase + ty + 16 * i;
        const float bi = bias[o];
#pragma unroll
        for (int j = 0; j < 4; ++j) {
            const int l = lBase + tx + 16 * j;
            Yb[(size_t)o * L_ + l] = (acc[i][j] + bi) * scale;
        }
    }
}

// ---------------------------------------------------------------------------
// Flash-style attention with relative-position bias (window +-4).
// Q,K,V in (B,C,L) fp32 (Q pre-scaled by Dh^-0.5). Output O in (B,H,L,Dh).
// Block: 256 threads, 32 query rows, key tiles of 64, online softmax.
// ---------------------------------------------------------------------------
__global__ __launch_bounds__(256) void attn_kernel(
    const float* __restrict__ Q, const float* __restrict__ K,
    const float* __restrict__ V,
    const float* __restrict__ erel_k, const float* __restrict__ erel_v,
    float* __restrict__ O)
{
    __shared__ float qs[32][65];    // qs[r][d]
    __shared__ float kst[64][68];   // kst[d][j]   (transposed K tile)
    __shared__ float vs[64][68];    // vs[j][d]
    __shared__ float S[32][68];     // scores / probs
    __shared__ float erk[9][65];
    __shared__ float erv[9][65];
    __shared__ float rs[32][9];     // per-row rel-k scores
    __shared__ float rv[32][9];     // per-row windowed prob accumulators
    __shared__ float mrow[32], lrow[32], arow[32];

    const int t  = threadIdx.x;
    const int bh = blockIdx.y;            // 0..63
    const int lt = blockIdx.x;            // query tile: rows lt*32 .. lt*32+31
    const int b  = bh >> 3, h = bh & 7;
    const size_t headOff = ((size_t)b * C_ + h * DH) * L_;  // row h*64+d, col l

    // preload relative embeddings
    for (int i = t; i < 9 * 64; i += 256) {
        erk[i >> 6][i & 63] = erel_k[i];
        erv[i >> 6][i & 63] = erel_v[i];
    }
    // load Q tile: qs[r][d]
    {
        const int rr = t & 31, d0 = t >> 5;
#pragma unroll
        for (int p = 0; p < 8; ++p) {
            const int d = d0 + 8 * p;
            qs[rr][d] = Q[headOff + (size_t)d * L_ + lt * 32 + rr];
        }
    }
    if (t < 32) { mrow[t] = -INFINITY; lrow[t] = 0.f; }
    for (int i = t; i < 32 * 9; i += 256) rv[i / 9][i % 9] = 0.f;
    __syncthreads();

    // per-row relative-k scores: rs[r][dr] = qs[r] . erk[dr]
    for (int idx = t; idx < 32 * 9; idx += 256) {
        const int r = idx / 9, dr = idx % 9;
        float s = 0.f;
        for (int d = 0; d < 64; ++d) s += qs[r][d] * erk[dr][d];
        rs[r][dr] = s;
    }

    float acc[2][4] = {};                 // O accumulators
    const int db  = t & 15;               // d block: d = db*4 .. +3
    const int rbp = t >> 4;               // row pair: r = rbp*2, rbp*2+1
    __syncthreads();                      // rs ready before S-compute uses it

    for (int jt = 0; jt < L_ / 64; ++jt) {
        // ---- stage K (transposed) and V tiles ----
        // 64 j x 64 d = 4096 elements each; 256 threads x 16 iters.
        {
            const int jj = t & 63, d0 = t >> 6;   // d0 in 0..3
#pragma unroll
            for (int p = 0; p < 16; ++p) {
                const int d = d0 + 4 * p;         // covers 0..63
                const size_t g = headOff + (size_t)d * L_ + jt * 64 + jj;
                kst[d][jj] = K[g];
                vs[jj][d]  = V[g];
            }
        }
        __syncthreads();

        // ---- S = Q K^T (+ windowed rel bias) ----
        {
            float sacc[2][4] = {};
#pragma unroll 8
            for (int d = 0; d < 64; ++d) {
                const float4 kv = *reinterpret_cast<const float4*>(&kst[d][db * 4]);
                const float q0 = qs[rbp * 2][d];
                const float q1 = qs[rbp * 2 + 1][d];
                sacc[0][0] += q0 * kv.x; sacc[0][1] += q0 * kv.y;
                sacc[0][2] += q0 * kv.z; sacc[0][3] += q0 * kv.w;
                sacc[1][0] += q1 * kv.x; sacc[1][1] += q1 * kv.y;
                sacc[1][2] += q1 * kv.z; sacc[1][3] += q1 * kv.w;
            }
#pragma unroll
            for (int i = 0; i < 2; ++i) {
                const int r  = rbp * 2 + i;
                const int lg = lt * 32 + r;
#pragma unroll
                for (int m = 0; m < 4; ++m) {
                    const int jg   = jt * 64 + db * 4 + m;
                    const int diff = jg - lg;
                    float s = sacc[i][m];
                    if (diff >= -WIN && diff <= WIN) s += rs[r][diff + WIN];
                    S[r][db * 4 + m] = s;
                }
            }
        }
        __syncthreads();

        // ---- row max + alpha ----
        if (t < 32) {
            float mx = -INFINITY;
            for (int j = 0; j < 64; ++j) mx = fmaxf(mx, S[t][j]);
            const float mold = mrow[t];
            const float mnew = fmaxf(mold, mx);
            arow[t] = expf(mold - mnew);
            mrow[t] = mnew;
        }
        __syncthreads();

        // ---- exponentiate ----
        for (int e = t; e < 32 * 64; e += 256) {
            const int r = e >> 6, j = e & 63;
            S[r][j] = expf(S[r][j] - mrow[r]);
        }
        __syncthreads();

        // ---- rel-v prob accumulators + row sums ----
        for (int idx = t; idx < 32 * 9; idx += 256) {
            const int r = idx / 9, dr = idx % 9;
            const int lg = lt * 32 + r;
            const int jg = lg + dr - WIN;
            float add = 0.f;
            if (jg >= jt * 64 && jg < jt * 64 + 64 && jg >= 0 && jg < L_)
                add = S[r][jg - jt * 64];
            rv[r][dr] = rv[r][dr] * arow[r] + add;
        }
        if (t < 32) {
            float sm = 0.f;
            for (int j = 0; j < 64; ++j) sm += S[t][j];
            lrow[t] = lrow[t] * arow[t] + sm;
        }

        // ---- rescale O accumulators, then O += P V ----
        {
            const float a0 = arow[rbp * 2];
            const float a1 = arow[rbp * 2 + 1];
#pragma unroll
            for (int m = 0; m < 4; ++m) { acc[0][m] *= a0; acc[1][m] *= a1; }
#pragma unroll 8
            for (int j = 0; j < 64; ++j) {
                const float4 vv = *reinterpret_cast<const float4*>(&vs[j][db * 4]);
                const float p0 = S[rbp * 2][j];
                const float p1 = S[rbp * 2 + 1][j];
                acc[0][0] += p0 * vv.x; acc[0][1] += p0 * vv.y;
                acc[0][2] += p0 * vv.z; acc[0][3] += p0 * vv.w;
                acc[1][0] += p1 * vv.x; acc[1][1] += p1 * vv.y;
                acc[1][2] += p1 * vv.z; acc[1][3] += p1 * vv.w;
            }
        }
        __syncthreads();   // protect kst/vs/S before next tile's staging
    }

    // ---- epilogue: add rel-v term, normalize, store (B,H,L,Dh) ----
#pragma unroll
    for (int i = 0; i < 2; ++i) {
        const int r  = rbp * 2 + i;
        const int lg = lt * 32 + r;
        const float inv = 1.f / lrow[r];
        float outv[4];
#pragma unroll
        for (int m = 0; m < 4; ++m) outv[m] = acc[i][m];
        for (int dr = 0; dr < 9; ++dr) {
            const float p = rv[r][dr];
#pragma unroll
            for (int m = 0; m < 4; ++m) outv[m] += p * erv[dr][db * 4 + m];
        }
        float4 st;
        st.x = outv[0] * inv; st.y = outv[1] * inv;
        st.z = outv[2] * inv; st.w = outv[3] * inv;
        *reinterpret_cast<float4*>(
            &O[(((size_t)bh) * L_ + lg) * DH + db * 4]) = st;
    }
}

// ---------------------------------------------------------------------------
extern "C" void kernel_launch(void* const* d_in, const int* in_sizes, int n_in,
                              void* d_out, int out_size, void* d_ws, size_t ws_size,
                              hipStream_t stream)
{
    const float* x   = (const float*)d_in[0];
    const float* Wq  = (const float*)d_in[1];
    const float* bq  = (const float*)d_in[2];
    const float* Wk  = (const float*)d_in[3];
    const float* bk  = (const float*)d_in[4];
    const float* Wv  = (const float*)d_in[5];
    const float* bv  = (const float*)d_in[6];
    const float* Wo  = (const float*)d_in[7];
    const float* bo  = (const float*)d_in[8];
    const float* erk = (const float*)d_in[9];
    const float* erv = (const float*)d_in[10];

    float* ws = (float*)d_ws;
    const size_t NELT = (size_t)B_ * C_ * L_;   // 4,194,304
    float* Q  = ws;
    float* K  = ws + NELT;
    float* V  = ws + 2 * NELT;
    float* AO = ws + 3 * NELT;                  // (B,H,L,Dh)

    const float scale = 0.125f;                 // Dh^-0.5 = 1/8

    dim3 gridG(L_ / 64, C_ / 64, B_);
    gemm_kernel<0><<<gridG, 256, 0, stream>>>(Wq, bq, x, Q, scale);
    gemm_kernel<0><<<gridG, 256, 0, stream>>>(Wk, bk, x, K, 1.0f);
    gemm_kernel<0><<<gridG, 256, 0, stream>>>(Wv, bv, x, V, 1.0f);

    dim3 gridA(L_ / 32, B_ * H_);
    attn_kernel<<<gridA, 256, 0, stream>>>(Q, K, V, erk, erv, AO);

    gemm_kernel<1><<<gridG, 256, 0, stream>>>(Wo, bo, AO, (float*)d_out, 1.0f);
}

// Round 3
// 338.691 us; speedup vs baseline: 2.4537x; 2.4537x over previous
//
#include <hip/hip_runtime.h>
#include <math.h>

#define B_  8
#define H_  8
#define C_  512
#define L_  1024
#define DH  64
#define WIN 4

typedef __attribute__((ext_vector_type(8))) short short8;
typedef __attribute__((ext_vector_type(4))) float floatx4;

__device__ __forceinline__ unsigned short f2bf(float f) {
    unsigned int u = __float_as_uint(f);
    u = u + 0x7FFFu + ((u >> 16) & 1u);     // RNE
    return (unsigned short)(u >> 16);
}
__device__ __forceinline__ float bf2f(unsigned short h) {
    return __uint_as_float(((unsigned int)h) << 16);
}

// ---------------------------------------------------------------------------
// Kernel 0: x (B,C,L) fp32 -> xT hi/lo bf16 in (B,L,C).  32x32 LDS transpose.
// ---------------------------------------------------------------------------
__global__ __launch_bounds__(256) void transpose_split_kernel(
    const float* __restrict__ x, unsigned short* __restrict__ xT_hi,
    unsigned short* __restrict__ xT_lo)
{
    __shared__ float tile[32][33];
    const int b  = blockIdx.z;
    const int cb = blockIdx.y * 32;
    const int lb = blockIdx.x * 32;
    const int t  = threadIdx.x;
    {
        const int l = t & 31, c0 = t >> 5;
#pragma unroll
        for (int p = 0; p < 4; ++p) {
            const int c = c0 + 8 * p;
            tile[c][l] = x[((size_t)b * C_ + cb + c) * L_ + lb + l];
        }
    }
    __syncthreads();
    {
        const int c = t & 31, l0 = t >> 5;
#pragma unroll
        for (int p = 0; p < 4; ++p) {
            const int l = l0 + 8 * p;
            const float v  = tile[c][l];
            const unsigned short hi = f2bf(v);
            const unsigned short lo = f2bf(v - bf2f(hi));
            const size_t idx = ((size_t)b * L_ + lb + l) * C_ + cb + c;
            xT_hi[idx] = hi;
            xT_lo[idx] = lo;
        }
    }
}

// ---------------------------------------------------------------------------
// MFMA GEMM: Y = W @ X + bias, per batch.  M=512(o) x N=1024(l) x K=512(c).
// A = W (fp32 (C,C), converted hi/lo in staging), split 3-term bf16 product.
// IMODE 0: X = xT hi/lo bf16 (B,L,C)          (pre-split, direct copy)
// IMODE 1: X = AO fp32 (B,H,L,Dh), logical x[c][l] = AO[b][c>>6][l][c&63]
// OMODE 0: store bf16 scaled to (B,H,L,Dh)    (Q, K)
// OMODE 1: store bf16 to (B,C,L)              (V)
// OMODE 2: store fp32 to (B,C,L)              (final out)
// Tile 128x128xBK32, 256 threads (2x2 waves of 64x64), 16x16x32 MFMA.
// ---------------------------------------------------------------------------
template <int IMODE, int OMODE>
__global__ __launch_bounds__(256) void mfma_gemm_kernel(
    const float* __restrict__ W, const float* __restrict__ bias,
    const void* __restrict__ Xa, const void* __restrict__ Xb,
    void* __restrict__ Y, float scale)
{
    __shared__ __align__(16) unsigned short As_hi[128][40];
    __shared__ __align__(16) unsigned short As_lo[128][40];
    __shared__ __align__(16) unsigned short Bs_hi[128][40];
    __shared__ __align__(16) unsigned short Bs_lo[128][40];

    const int b  = blockIdx.z;
    const int ob = blockIdx.y * 128;
    const int lb = blockIdx.x * 128;
    const int t  = threadIdx.x;
    const int w    = t >> 6;
    const int lane = t & 63;
    const int quad = lane >> 4;
    const int lc   = lane & 15;
    const int wm = w >> 1, wn = w & 1;

    floatx4 acc[4][4];
#pragma unroll
    for (int i = 0; i < 4; ++i)
#pragma unroll
        for (int j = 0; j < 4; ++j) acc[i][j] = (floatx4)0.f;

    for (int c0 = 0; c0 < C_; c0 += 32) {
        // ---- stage W tile (128 o x 32 c) with hi/lo split ----
        {
            const int c4 = (t & 7) * 4, o0 = t >> 3;
#pragma unroll
            for (int p = 0; p < 4; ++p) {
                const int o = o0 + 32 * p;
                const float4 wv = *reinterpret_cast<const float4*>(
                    &W[(size_t)(ob + o) * C_ + c0 + c4]);
                unsigned short h0 = f2bf(wv.x), h1 = f2bf(wv.y),
                               h2 = f2bf(wv.z), h3 = f2bf(wv.w);
                unsigned short l0 = f2bf(wv.x - bf2f(h0)), l1 = f2bf(wv.y - bf2f(h1)),
                               l2 = f2bf(wv.z - bf2f(h2)), l3 = f2bf(wv.w - bf2f(h3));
                uint2 hv, lv;
                hv.x = (unsigned)h0 | ((unsigned)h1 << 16);
                hv.y = (unsigned)h2 | ((unsigned)h3 << 16);
                lv.x = (unsigned)l0 | ((unsigned)l1 << 16);
                lv.y = (unsigned)l2 | ((unsigned)l3 << 16);
                *reinterpret_cast<uint2*>(&As_hi[o][c4]) = hv;
                *reinterpret_cast<uint2*>(&As_lo[o][c4]) = lv;
            }
        }
        // ---- stage X tile (128 l x 32 c) as [l][c] ----
        if (IMODE == 0) {
            const unsigned short* xh = (const unsigned short*)Xa;
            const unsigned short* xl = (const unsigned short*)Xb;
            const int c8 = (t & 3) * 8, l0 = t >> 2;
#pragma unroll
            for (int p = 0; p < 2; ++p) {
                const int l = l0 + 64 * p;
                const size_t g = ((size_t)b * L_ + lb + l) * C_ + c0 + c8;
                *reinterpret_cast<uint4*>(&Bs_hi[l][c8]) =
                    *reinterpret_cast<const uint4*>(&xh[g]);
                *reinterpret_cast<uint4*>(&Bs_lo[l][c8]) =
                    *reinterpret_cast<const uint4*>(&xl[g]);
            }
        } else {
            const float* ao = (const float*)Xa;
            const int c4 = (t & 7) * 4, l0 = t >> 3;
            const int cg = c0 + c4;
            const int h = cg >> 6, d = cg & 63;
#pragma unroll
            for (int p = 0; p < 4; ++p) {
                const int l = l0 + 32 * p;
                const float4 v = *reinterpret_cast<const float4*>(
                    &ao[(((size_t)b * H_ + h) * L_ + lb + l) * DH + d]);
                unsigned short h0 = f2bf(v.x), h1 = f2bf(v.y),
                               h2 = f2bf(v.z), h3 = f2bf(v.w);
                unsigned short q0 = f2bf(v.x - bf2f(h0)), q1 = f2bf(v.y - bf2f(h1)),
                               q2 = f2bf(v.z - bf2f(h2)), q3 = f2bf(v.w - bf2f(h3));
                uint2 hv, lv;
                hv.x = (unsigned)h0 | ((unsigned)h1 << 16);
                hv.y = (unsigned)h2 | ((unsigned)h3 << 16);
                lv.x = (unsigned)q0 | ((unsigned)q1 << 16);
                lv.y = (unsigned)q2 | ((unsigned)q3 << 16);
                *reinterpret_cast<uint2*>(&Bs_hi[l][c4]) = hv;
                *reinterpret_cast<uint2*>(&Bs_lo[l][c4]) = lv;
            }
        }
        __syncthreads();

        // ---- 48 MFMAs: 4x4 tiles x 3 split terms ----
        short8 ah[4], al[4], bh[4], bl[4];
#pragma unroll
        for (int mt = 0; mt < 4; ++mt) {
            const int row = wm * 64 + mt * 16 + lc;
            ah[mt] = *reinterpret_cast<const short8*>(&As_hi[row][quad * 8]);
            al[mt] = *reinterpret_cast<const short8*>(&As_lo[row][quad * 8]);
        }
#pragma unroll
        for (int nt = 0; nt < 4; ++nt) {
            const int rowb = wn * 64 + nt * 16 + lc;
            bh[nt] = *reinterpret_cast<const short8*>(&Bs_hi[rowb][quad * 8]);
            bl[nt] = *reinterpret_cast<const short8*>(&Bs_lo[rowb][quad * 8]);
        }
#pragma unroll
        for (int mt = 0; mt < 4; ++mt)
#pragma unroll
            for (int nt = 0; nt < 4; ++nt) {
                acc[mt][nt] = __builtin_amdgcn_mfma_f32_16x16x32_bf16(
                    ah[mt], bh[nt], acc[mt][nt], 0, 0, 0);
                acc[mt][nt] = __builtin_amdgcn_mfma_f32_16x16x32_bf16(
                    ah[mt], bl[nt], acc[mt][nt], 0, 0, 0);
                acc[mt][nt] = __builtin_amdgcn_mfma_f32_16x16x32_bf16(
                    al[mt], bh[nt], acc[mt][nt], 0, 0, 0);
            }
        __syncthreads();
    }

    // ---- epilogue ----
#pragma unroll
    for (int mt = 0; mt < 4; ++mt) {
#pragma unroll
        for (int r = 0; r < 4; ++r) {
            const int o = ob + wm * 64 + mt * 16 + quad * 4 + r;
            const float bi = bias[o];
#pragma unroll
            for (int nt = 0; nt < 4; ++nt) {
                const int l = lb + wn * 64 + nt * 16 + lc;
                const float val = (acc[mt][nt][r] + bi) * scale;
                if (OMODE == 0) {
                    const int h = o >> 6, d = o & 63;
                    ((unsigned short*)Y)[(((size_t)b * H_ + h) * L_ + l) * DH + d] = f2bf(val);
                } else if (OMODE == 1) {
                    ((unsigned short*)Y)[((size_t)b * C_ + o) * L_ + l] = f2bf(val);
                } else {
                    ((float*)Y)[((size_t)b * C_ + o) * L_ + l] = val;
                }
            }
        }
    }
}

// ---------------------------------------------------------------------------
// MFMA flash attention with windowed relative bias.
// Qb,Kb bf16 (B,H,L,Dh) (Q pre-scaled), Vb bf16 (B,C,L).  AO fp32 (B,H,L,Dh).
// Block: 256 thr = 4 waves; 64 q-rows/block (16 per wave), 64-key tiles.
// ---------------------------------------------------------------------------
__global__ __launch_bounds__(256) void attn_mfma_kernel(
    const unsigned short* __restrict__ Qb, const unsigned short* __restrict__ Kb,
    const unsigned short* __restrict__ Vb,
    const float* __restrict__ erel_k, const float* __restrict__ erel_v,
    float* __restrict__ AO)
{
    __shared__ __align__(16) unsigned short qs [64][72];  // [l][d]  A-op QK^T
    __shared__ __align__(16) unsigned short kst[64][72];  // [j][d]  B-op QK^T
    __shared__ __align__(16) unsigned short vsT[64][72];  // [d][j]  B-op PV
    __shared__ __align__(16) unsigned short Pl [64][72];  // [l][j]  A-op PV
    __shared__ float erk_l[9][64], erv_l[9][64];
    __shared__ float rs[64][9];     // rel-k scores per row
    __shared__ float rv[64][9];     // rel-v prob accumulators
    __shared__ float arow[64];

    const int t   = threadIdx.x;
    const int bh  = blockIdx.y;
    const int qb0 = blockIdx.x * 64;
    const int b = bh >> 3, h = bh & 7;
    const int w    = t >> 6;
    const int lane = t & 63;
    const int quad = lane >> 4;
    const int lc   = lane & 15;

    const size_t qkBase = (size_t)bh * L_ * DH;
    const size_t vBase  = ((size_t)b * C_ + h * DH) * L_;

    // ---- one-time staging ----
    for (int i = t; i < 9 * 64; i += 256) {
        erk_l[i / 64][i % 64] = erel_k[i];
        erv_l[i / 64][i % 64] = erel_v[i];
    }
    {
        const int d8 = (t & 7) * 8, l0 = t >> 3;
#pragma unroll
        for (int p = 0; p < 2; ++p) {
            const int l = l0 + 32 * p;
            *reinterpret_cast<uint4*>(&qs[l][d8]) =
                *reinterpret_cast<const uint4*>(&Qb[qkBase + (size_t)(qb0 + l) * DH + d8]);
        }
    }
    for (int i = t; i < 64 * 9; i += 256) rv[i / 9][i % 9] = 0.f;
    __syncthreads();

    // rel-k scores: rs[r][dr] = q_r . erk[dr]
    for (int idx = t; idx < 64 * 9; idx += 256) {
        const int r = idx / 9, dr = idx % 9;
        float s = 0.f;
        for (int d = 0; d < 64; ++d) s += bf2f(qs[r][d]) * erk_l[dr][d];
        rs[r][dr] = s;
    }
    __syncthreads();

    float m[4], lsum[4];
#pragma unroll
    for (int r = 0; r < 4; ++r) { m[r] = -INFINITY; lsum[r] = 0.f; }
    floatx4 acc_o[4];
#pragma unroll
    for (int nt = 0; nt < 4; ++nt) acc_o[nt] = (floatx4)0.f;

    for (int jt = 0; jt < L_ / 64; ++jt) {
        // ---- stage K tile [j][d] and V tile [d][j] ----
        {
            const int d8 = (t & 7) * 8, j0 = t >> 3;
#pragma unroll
            for (int p = 0; p < 2; ++p) {
                const int j = j0 + 32 * p;
                *reinterpret_cast<uint4*>(&kst[j][d8]) =
                    *reinterpret_cast<const uint4*>(
                        &Kb[qkBase + (size_t)(jt * 64 + j) * DH + d8]);
            }
        }
        {
            const int j8 = (t & 7) * 8, d0 = t >> 3;
#pragma unroll
            for (int p = 0; p < 2; ++p) {
                const int d = d0 + 32 * p;
                *reinterpret_cast<uint4*>(&vsT[d][j8]) =
                    *reinterpret_cast<const uint4*>(
                        &Vb[vBase + (size_t)d * L_ + jt * 64 + j8]);
            }
        }
        __syncthreads();

        // ---- S = Q K^T via MFMA ----
        floatx4 sacc[4];
#pragma unroll
        for (int nt = 0; nt < 4; ++nt) sacc[nt] = (floatx4)0.f;
        short8 af[2];
#pragma unroll
        for (int kk = 0; kk < 2; ++kk)
            af[kk] = *reinterpret_cast<const short8*>(&qs[w * 16 + lc][kk * 32 + quad * 8]);
#pragma unroll
        for (int nt = 0; nt < 4; ++nt)
#pragma unroll
            for (int kk = 0; kk < 2; ++kk) {
                const short8 bf = *reinterpret_cast<const short8*>(
                    &kst[nt * 16 + lc][kk * 32 + quad * 8]);
                sacc[nt] = __builtin_amdgcn_mfma_f32_16x16x32_bf16(af[kk], bf, sacc[nt], 0, 0, 0);
            }

        // ---- windowed rel-k bias (C/D layout: row=quad*4+r, col=nt*16+lc) ----
#pragma unroll
        for (int nt = 0; nt < 4; ++nt) {
            const int jg = jt * 64 + nt * 16 + lc;
#pragma unroll
            for (int r = 0; r < 4; ++r) {
                const int row = w * 16 + quad * 4 + r;
                const int diff = jg - (qb0 + row);
                if (diff >= -WIN && diff <= WIN) sacc[nt][r] += rs[row][diff + WIN];
            }
        }

        // ---- online softmax (per row, 16-lane quad reductions) ----
#pragma unroll
        for (int r = 0; r < 4; ++r) {
            float mx = fmaxf(fmaxf(sacc[0][r], sacc[1][r]), fmaxf(sacc[2][r], sacc[3][r]));
            mx = fmaxf(mx, __shfl_xor(mx, 1));
            mx = fmaxf(mx, __shfl_xor(mx, 2));
            mx = fmaxf(mx, __shfl_xor(mx, 4));
            mx = fmaxf(mx, __shfl_xor(mx, 8));
            const float mn = fmaxf(m[r], mx);
            const float al = __expf(m[r] - mn);
            m[r] = mn;
#pragma unroll
            for (int nt = 0; nt < 4; ++nt) sacc[nt][r] = __expf(sacc[nt][r] - mn);
            float sm = sacc[0][r] + sacc[1][r] + sacc[2][r] + sacc[3][r];
            sm += __shfl_xor(sm, 1);
            sm += __shfl_xor(sm, 2);
            sm += __shfl_xor(sm, 4);
            sm += __shfl_xor(sm, 8);
            lsum[r] = lsum[r] * al + sm;
#pragma unroll
            for (int nt = 0; nt < 4; ++nt) acc_o[nt][r] *= al;
            if (lc == 0) arow[w * 16 + quad * 4 + r] = al;
        }

        // ---- P -> LDS (bf16, A-operand round-trip); same-wave rows only ----
#pragma unroll
        for (int nt = 0; nt < 4; ++nt)
#pragma unroll
            for (int r = 0; r < 4; ++r)
                Pl[w * 16 + quad * 4 + r][nt * 16 + lc] = f2bf(sacc[nt][r]);

        // ---- rel-v accumulators (rows owned by this wave) ----
        for (int idx = lane; idx < 16 * 9; idx += 64) {
            const int r16 = idx / 9, dr = idx % 9;
            const int row = w * 16 + r16;
            const int lg = qb0 + row;
            const int jg = lg + dr - WIN;
            float add = 0.f;
            if (jg >= jt * 64 && jg < jt * 64 + 64 && jg >= 0 && jg < L_)
                add = bf2f(Pl[row][jg - jt * 64]);
            rv[row][dr] = rv[row][dr] * arow[row] + add;
        }

        // ---- O += P V via MFMA ----
        short8 pf[2];
#pragma unroll
        for (int kk = 0; kk < 2; ++kk)
            pf[kk] = *reinterpret_cast<const short8*>(&Pl[w * 16 + lc][kk * 32 + quad * 8]);
#pragma unroll
        for (int nt = 0; nt < 4; ++nt)
#pragma unroll
            for (int kk = 0; kk < 2; ++kk) {
                const short8 vf = *reinterpret_cast<const short8*>(
                    &vsT[nt * 16 + lc][kk * 32 + quad * 8]);
                acc_o[nt] = __builtin_amdgcn_mfma_f32_16x16x32_bf16(pf[kk], vf, acc_o[nt], 0, 0, 0);
            }
        __syncthreads();   // protect kst/vsT for next tile
    }

    // ---- epilogue: rel-v term, normalize, store AO (B,H,L,Dh) fp32 ----
#pragma unroll
    for (int nt = 0; nt < 4; ++nt) {
        const int d = nt * 16 + lc;
#pragma unroll
        for (int r = 0; r < 4; ++r) {
            const int row = w * 16 + quad * 4 + r;
            float v = acc_o[nt][r];
            for (int dr = 0; dr < 9; ++dr) v += rv[row][dr] * erv_l[dr][d];
            AO[((size_t)bh * L_ + qb0 + row) * DH + d] = v / lsum[r];
        }
    }
}

// ---------------------------------------------------------------------------
extern "C" void kernel_launch(void* const* d_in, const int* in_sizes, int n_in,
                              void* d_out, int out_size, void* d_ws, size_t ws_size,
                              hipStream_t stream)
{
    const float* x   = (const float*)d_in[0];
    const float* Wq  = (const float*)d_in[1];
    const float* bq  = (const float*)d_in[2];
    const float* Wk  = (const float*)d_in[3];
    const float* bk  = (const float*)d_in[4];
    const float* Wv  = (const float*)d_in[5];
    const float* bv  = (const float*)d_in[6];
    const float* Wo  = (const float*)d_in[7];
    const float* bo  = (const float*)d_in[8];
    const float* erk = (const float*)d_in[9];
    const float* erv = (const float*)d_in[10];

    char* ws = (char*)d_ws;
    const size_t NELT = (size_t)B_ * C_ * L_;          // 4,194,304
    float*          AO    = (float*)ws;                 // 16 MB fp32 (B,H,L,Dh)
    unsigned short* xT_hi = (unsigned short*)(ws + 16u * 1024 * 1024);
    unsigned short* xT_lo = (unsigned short*)(ws + 24u * 1024 * 1024);
    unsigned short* Qb    = (unsigned short*)(ws + 32u * 1024 * 1024);
    unsigned short* Kb    = (unsigned short*)(ws + 40u * 1024 * 1024);
    unsigned short* Vb    = (unsigned short*)(ws + 48u * 1024 * 1024);
    (void)NELT; (void)ws_size;

    // 1) transpose + hi/lo split of x
    transpose_split_kernel<<<dim3(L_ / 32, C_ / 32, B_), 256, 0, stream>>>(x, xT_hi, xT_lo);

    // 2) Q/K/V projections (MFMA, split)
    dim3 gridG(L_ / 128, C_ / 128, B_);
    mfma_gemm_kernel<0, 0><<<gridG, 256, 0, stream>>>(Wq, bq, xT_hi, xT_lo, Qb, 0.125f);
    mfma_gemm_kernel<0, 0><<<gridG, 256, 0, stream>>>(Wk, bk, xT_hi, xT_lo, Kb, 1.0f);
    mfma_gemm_kernel<0, 1><<<gridG, 256, 0, stream>>>(Wv, bv, xT_hi, xT_lo, Vb, 1.0f);

    // 3) flash attention with relative bias
    attn_mfma_kernel<<<dim3(L_ / 64, B_ * H_), 256, 0, stream>>>(Qb, Kb, Vb, erk, erv, AO);

    // 4) output projection (MFMA, split) -> fp32 d_out
    mfma_gemm_kernel<1, 2><<<gridG, 256, 0, stream>>>(Wo, bo, AO, nullptr, d_out, 1.0f);
}

// Round 4
// 267.955 us; speedup vs baseline: 3.1014x; 1.2640x over previous
//
#include <hip/hip_runtime.h>
#include <math.h>

#define B_  8
#define H_  8
#define C_  512
#define L_  1024
#define DH  64
#define WIN 4

typedef __attribute__((ext_vector_type(8))) short short8;
typedef __attribute__((ext_vector_type(4))) float floatx4;

__device__ __forceinline__ unsigned short f2bf(float f) {
    unsigned int u = __float_as_uint(f);
    u = u + 0x7FFFu + ((u >> 16) & 1u);     // RNE
    return (unsigned short)(u >> 16);
}
__device__ __forceinline__ float bf2f(unsigned short h) {
    return __uint_as_float(((unsigned int)h) << 16);
}

// ---------------------------------------------------------------------------
// prep: Wq/Wk/Wv -> bf16 hi (packed 3x512x512), Wo -> hi+lo, pack biases.
// grid 256 x 256 threads, one float4 per thread per matrix.
// ---------------------------------------------------------------------------
__global__ __launch_bounds__(256) void prep_kernel(
    const float* __restrict__ Wq, const float* __restrict__ Wk,
    const float* __restrict__ Wv, const float* __restrict__ Wo,
    const float* __restrict__ bq, const float* __restrict__ bk,
    const float* __restrict__ bv,
    unsigned short* __restrict__ Wqkv_hi,
    unsigned short* __restrict__ Wo_hi, unsigned short* __restrict__ Wo_lo,
    float* __restrict__ bqkv)
{
    const int i = blockIdx.x * 256 + threadIdx.x;   // 65536 float4 slots
    float4 v; ushort4 h;

    v = ((const float4*)Wq)[i];
    h.x = f2bf(v.x); h.y = f2bf(v.y); h.z = f2bf(v.z); h.w = f2bf(v.w);
    ((ushort4*)Wqkv_hi)[i] = h;

    v = ((const float4*)Wk)[i];
    h.x = f2bf(v.x); h.y = f2bf(v.y); h.z = f2bf(v.z); h.w = f2bf(v.w);
    ((ushort4*)Wqkv_hi)[65536 + i] = h;

    v = ((const float4*)Wv)[i];
    h.x = f2bf(v.x); h.y = f2bf(v.y); h.z = f2bf(v.z); h.w = f2bf(v.w);
    ((ushort4*)Wqkv_hi)[131072 + i] = h;

    v = ((const float4*)Wo)[i];
    h.x = f2bf(v.x); h.y = f2bf(v.y); h.z = f2bf(v.z); h.w = f2bf(v.w);
    ((ushort4*)Wo_hi)[i] = h;
    ushort4 lo;
    lo.x = f2bf(v.x - bf2f(h.x)); lo.y = f2bf(v.y - bf2f(h.y));
    lo.z = f2bf(v.z - bf2f(h.z)); lo.w = f2bf(v.w - bf2f(h.w));
    ((ushort4*)Wo_lo)[i] = lo;

    if (i < 512)       bqkv[i] = bq[i];
    else if (i < 1024) bqkv[i] = bk[i - 512];
    else if (i < 1536) bqkv[i] = bv[i - 1024];
}

// ---------------------------------------------------------------------------
// x (B,C,L) fp32 -> xT bf16 (B,L,C).  32x32 LDS transpose.
// ---------------------------------------------------------------------------
__global__ __launch_bounds__(256) void transpose_kernel(
    const float* __restrict__ x, unsigned short* __restrict__ xT)
{
    __shared__ float tile[32][33];
    const int b  = blockIdx.z;
    const int cb = blockIdx.y * 32;
    const int lb = blockIdx.x * 32;
    const int t  = threadIdx.x;
    {
        const int l = t & 31, c0 = t >> 5;
#pragma unroll
        for (int p = 0; p < 4; ++p) {
            const int c = c0 + 8 * p;
            tile[c][l] = x[((size_t)b * C_ + cb + c) * L_ + lb + l];
        }
    }
    __syncthreads();
    {
        const int c = t & 31, l0 = t >> 5;
#pragma unroll
        for (int p = 0; p < 4; ++p) {
            const int l = l0 + 8 * p;
            xT[((size_t)b * L_ + lb + l) * C_ + cb + c] = f2bf(tile[c][l]);
        }
    }
}

// ---------------------------------------------------------------------------
// Fused QKV GEMM, plain bf16 (1 term).  M=1536 (3 matrices) x N=1024 x K=512.
// A = Wqkv_hi (3,512,512), B = xT (B,L,C).  Tile 128x128xBK32, 4 waves 2x2.
// Q -> (B,H,L,Dh) bf16 scaled; K -> (B,H,L,Dh) bf16; V -> (B,C,L) bf16.
// ---------------------------------------------------------------------------
__global__ __launch_bounds__(256) void qkv_gemm_kernel(
    const unsigned short* __restrict__ Wh, const float* __restrict__ bqkv,
    const unsigned short* __restrict__ xT,
    unsigned short* __restrict__ Qb, unsigned short* __restrict__ Kb,
    unsigned short* __restrict__ Vb)
{
    __shared__ __align__(16) unsigned short As[128][40];
    __shared__ __align__(16) unsigned short Bs[128][40];

    const int b   = blockIdx.z;
    const int oB  = blockIdx.y * 128;       // 0..1536
    const int mat = oB >> 9;                // 0=Q,1=K,2=V
    const int ob  = oB & 511;
    const int lb  = blockIdx.x * 128;
    const int t  = threadIdx.x;
    const int w = t >> 6, lane = t & 63, quad = lane >> 4, lc = lane & 15;
    const int wm = w >> 1, wn = w & 1;

    const unsigned short* Wm = Wh + (size_t)mat * C_ * C_;

    floatx4 acc[4][4];
#pragma unroll
    for (int i = 0; i < 4; ++i)
#pragma unroll
        for (int j = 0; j < 4; ++j) acc[i][j] = (floatx4)0.f;

    const int c8 = (t & 3) * 8, r0 = t >> 2;   // 16B copies, rows r0, r0+64
    for (int c0 = 0; c0 < C_; c0 += 32) {
#pragma unroll
        for (int p = 0; p < 2; ++p) {
            *reinterpret_cast<uint4*>(&As[r0 + 64 * p][c8]) =
                *reinterpret_cast<const uint4*>(&Wm[(size_t)(ob + r0 + 64 * p) * C_ + c0 + c8]);
            *reinterpret_cast<uint4*>(&Bs[r0 + 64 * p][c8]) =
                *reinterpret_cast<const uint4*>(&xT[((size_t)b * L_ + lb + r0 + 64 * p) * C_ + c0 + c8]);
        }
        __syncthreads();

        short8 a[4], bb[4];
#pragma unroll
        for (int mt = 0; mt < 4; ++mt)
            a[mt] = *reinterpret_cast<const short8*>(&As[wm * 64 + mt * 16 + lc][quad * 8]);
#pragma unroll
        for (int nt = 0; nt < 4; ++nt)
            bb[nt] = *reinterpret_cast<const short8*>(&Bs[wn * 64 + nt * 16 + lc][quad * 8]);
#pragma unroll
        for (int mt = 0; mt < 4; ++mt)
#pragma unroll
            for (int nt = 0; nt < 4; ++nt)
                acc[mt][nt] = __builtin_amdgcn_mfma_f32_16x16x32_bf16(a[mt], bb[nt], acc[mt][nt], 0, 0, 0);
        __syncthreads();
    }

    const float scale = (mat == 0) ? 0.125f : 1.0f;
    unsigned short* dstQK = (mat == 0) ? Qb : Kb;
#pragma unroll
    for (int mt = 0; mt < 4; ++mt) {
#pragma unroll
        for (int r = 0; r < 4; ++r) {
            const int o  = ob + wm * 64 + mt * 16 + quad * 4 + r;
            const float bi = bqkv[mat * 512 + o];
#pragma unroll
            for (int nt = 0; nt < 4; ++nt) {
                const int l = lb + wn * 64 + nt * 16 + lc;
                const float val = (acc[mt][nt][r] + bi) * scale;
                if (mat < 2) {
                    const int hh = o >> 6, d = o & 63;
                    dstQK[(((size_t)b * H_ + hh) * L_ + l) * DH + d] = f2bf(val);
                } else {
                    Vb[((size_t)b * C_ + o) * L_ + l] = f2bf(val);
                }
            }
        }
    }
}

// ---------------------------------------------------------------------------
// Barrier-free MFMA flash attention, no-max softmax (scores bounded ~|6|).
// Qb,Kb bf16 (B,H,L,Dh) (Q pre-scaled), Vb bf16 (B,C,L).
// Out: AO hi/lo bf16 in (B,L,C).  4 waves x 16 q-rows, 16 key tiles of 64.
// K/V B-fragments loaded directly from global (L1-served); only P and the
// small rel-k/rel-v state touch LDS (all same-wave -> no in-loop barriers).
// ---------------------------------------------------------------------------
__global__ __launch_bounds__(256) void attn_kernel2(
    const unsigned short* __restrict__ Qb, const unsigned short* __restrict__ Kb,
    const unsigned short* __restrict__ Vb,
    const float* __restrict__ erel_k, const float* __restrict__ erel_v,
    unsigned short* __restrict__ AOh, unsigned short* __restrict__ AOl)
{
    __shared__ __align__(16) unsigned short Pl[64][72];   // [row][j] bf16 P
    __shared__ float rs[64][9];     // rel-k scores
    __shared__ float rv[64][9];     // rel-v prob sums
    __shared__ float erv_s[9][64];

    const int t   = threadIdx.x;
    const int bh  = blockIdx.y;
    const int qb0 = blockIdx.x * 64;
    const int b = bh >> 3, h = bh & 7;
    const int w = t >> 6, lane = t & 63, quad = lane >> 4, lc = lane & 15;

    const size_t qkBase = (size_t)bh * L_ * DH;
    const size_t vBase  = ((size_t)b * C_ + h * DH) * L_;

    for (int i = t; i < 9 * 64; i += 256) erv_s[i / 64][i % 64] = erel_v[i];
    for (int i = t; i < 64 * 9; i += 256) rv[i / 9][i % 9] = 0.f;

    // Q A-fragments (row = qb0 + w*16 + lc), reused across all tiles
    short8 af[2];
#pragma unroll
    for (int kk = 0; kk < 2; ++kk)
        af[kk] = *reinterpret_cast<const short8*>(
            &Qb[qkBase + (size_t)(qb0 + w * 16 + lc) * DH + kk * 32 + quad * 8]);

    // rel-k scores via MFMA: B[n=dr][k=d] = erk[dr][d] (bf16 on the fly)
    {
        floatx4 rsa = (floatx4)0.f;
        const int erow = (lc < 9) ? lc : 8;
#pragma unroll
        for (int kk = 0; kk < 2; ++kk) {
            const float* ep = erel_k + erow * 64 + kk * 32 + quad * 8;
            short8 bfr;
#pragma unroll
            for (int j = 0; j < 8; ++j) bfr[j] = (short)f2bf(ep[j]);
            rsa = __builtin_amdgcn_mfma_f32_16x16x32_bf16(af[kk], bfr, rsa, 0, 0, 0);
        }
        if (lc < 9) {
#pragma unroll
            for (int r = 0; r < 4; ++r) rs[w * 16 + quad * 4 + r][lc] = rsa[r];
        }
    }
    __syncthreads();   // rs/rv/erv ready (only cross-thread sync in kernel)

    float lsum[4] = {0.f, 0.f, 0.f, 0.f};
    floatx4 acc_o[4];
#pragma unroll
    for (int nt = 0; nt < 4; ++nt) acc_o[nt] = (floatx4)0.f;

    const int myRow0 = qb0 + w * 16;

    for (int jt = 0; jt < L_ / 64; ++jt) {
        const int j0 = jt * 64;

        // ---- S = Q K^T (K frags direct from global) ----
        floatx4 sacc[4];
#pragma unroll
        for (int nt = 0; nt < 4; ++nt) sacc[nt] = (floatx4)0.f;
#pragma unroll
        for (int nt = 0; nt < 4; ++nt)
#pragma unroll
            for (int kk = 0; kk < 2; ++kk) {
                const short8 kf = *reinterpret_cast<const short8*>(
                    &Kb[qkBase + (size_t)(j0 + nt * 16 + lc) * DH + kk * 32 + quad * 8]);
                sacc[nt] = __builtin_amdgcn_mfma_f32_16x16x32_bf16(af[kk], kf, sacc[nt], 0, 0, 0);
            }

        // ---- windowed rel-k bias (near-diagonal tiles only) ----
        const bool nearD = (j0 <= myRow0 + 15 + WIN) && (j0 + 63 >= myRow0 - WIN);
        if (nearD) {
#pragma unroll
            for (int nt = 0; nt < 4; ++nt) {
                const int jg = j0 + nt * 16 + lc;
#pragma unroll
                for (int r = 0; r < 4; ++r) {
                    const int row = w * 16 + quad * 4 + r;
                    const int diff = jg - (qb0 + row);
                    if (diff >= -WIN && diff <= WIN) sacc[nt][r] += rs[row][diff + WIN];
                }
            }
        }

        // ---- exp (no max subtraction), partial row sums, P -> LDS bf16 ----
#pragma unroll
        for (int nt = 0; nt < 4; ++nt)
#pragma unroll
            for (int r = 0; r < 4; ++r) {
                const float p = __expf(sacc[nt][r]);
                sacc[nt][r] = p;
                lsum[r] += p;
                Pl[w * 16 + quad * 4 + r][nt * 16 + lc] = f2bf(p);
            }

        // ---- rel-v prob accumulation (same-wave rows, gated) ----
        if (nearD) {
            for (int idx = lane; idx < 16 * 9; idx += 64) {
                const int r16 = idx / 9, dr = idx % 9;
                const int row = w * 16 + r16;
                const int jg  = qb0 + row + dr - WIN;
                if (jg >= j0 && jg < j0 + 64 && jg >= 0 && jg < L_)
                    rv[row][dr] += bf2f(Pl[row][jg - j0]);
            }
        }

        // ---- O += P V (P A-frags from LDS, V B-frags direct global) ----
        short8 pf[2];
#pragma unroll
        for (int kk = 0; kk < 2; ++kk)
            pf[kk] = *reinterpret_cast<const short8*>(&Pl[w * 16 + lc][kk * 32 + quad * 8]);
#pragma unroll
        for (int nt = 0; nt < 4; ++nt)
#pragma unroll
            for (int kk = 0; kk < 2; ++kk) {
                const short8 vf = *reinterpret_cast<const short8*>(
                    &Vb[vBase + (size_t)(nt * 16 + lc) * L_ + j0 + kk * 32 + quad * 8]);
                acc_o[nt] = __builtin_amdgcn_mfma_f32_16x16x32_bf16(pf[kk], vf, acc_o[nt], 0, 0, 0);
            }
    }

    // ---- one deferred row-sum reduction (16 lanes per quad-row) ----
#pragma unroll
    for (int r = 0; r < 4; ++r) {
        float s = lsum[r];
        s += __shfl_xor(s, 1); s += __shfl_xor(s, 2);
        s += __shfl_xor(s, 4); s += __shfl_xor(s, 8);
        lsum[r] = s;
    }

    // ---- epilogue: rel-v term, normalize, write AO hi/lo bf16 (B,L,C) ----
#pragma unroll
    for (int nt = 0; nt < 4; ++nt) {
        const int d = nt * 16 + lc;
#pragma unroll
        for (int r = 0; r < 4; ++r) {
            const int row = w * 16 + quad * 4 + r;
            float v = acc_o[nt][r];
            for (int dr = 0; dr < 9; ++dr) v += rv[row][dr] * erv_s[dr][d];
            const float outv = v / lsum[r];
            const unsigned short hi = f2bf(outv);
            const unsigned short lo = f2bf(outv - bf2f(hi));
            const size_t idx = ((size_t)b * L_ + qb0 + row) * C_ + h * 64 + d;
            AOh[idx] = hi;
            AOl[idx] = lo;
        }
    }
}

// ---------------------------------------------------------------------------
// Output projection, 3-term hi/lo split.  M=512 x N-tile 64 x K=512.
// A = Wo hi/lo, B = AO hi/lo (B,L,C).  512 blocks (2/CU).  Y fp32 (B,C,L).
// ---------------------------------------------------------------------------
__global__ __launch_bounds__(256) void out_gemm_kernel(
    const unsigned short* __restrict__ Wh, const unsigned short* __restrict__ Wl,
    const float* __restrict__ bo,
    const unsigned short* __restrict__ Ah, const unsigned short* __restrict__ Al,
    float* __restrict__ Y)
{
    __shared__ __align__(16) unsigned short As_h[128][40];
    __shared__ __align__(16) unsigned short As_l[128][40];
    __shared__ __align__(16) unsigned short Bs_h[64][40];
    __shared__ __align__(16) unsigned short Bs_l[64][40];

    const int b  = blockIdx.z;
    const int ob = blockIdx.y * 128;
    const int lb = blockIdx.x * 64;
    const int t  = threadIdx.x;
    const int w = t >> 6, lane = t & 63, quad = lane >> 4, lc = lane & 15;
    const int wm = w >> 1, wn = w & 1;     // wave tile: 64 M x 32 N

    floatx4 acc[4][2];
#pragma unroll
    for (int i = 0; i < 4; ++i)
#pragma unroll
        for (int j = 0; j < 2; ++j) acc[i][j] = (floatx4)0.f;

    const int c8 = (t & 3) * 8, r0 = t >> 2;
    for (int c0 = 0; c0 < C_; c0 += 32) {
#pragma unroll
        for (int p = 0; p < 2; ++p) {
            *reinterpret_cast<uint4*>(&As_h[r0 + 64 * p][c8]) =
                *reinterpret_cast<const uint4*>(&Wh[(size_t)(ob + r0 + 64 * p) * C_ + c0 + c8]);
            *reinterpret_cast<uint4*>(&As_l[r0 + 64 * p][c8]) =
                *reinterpret_cast<const uint4*>(&Wl[(size_t)(ob + r0 + 64 * p) * C_ + c0 + c8]);
        }
        {
            const size_t g = ((size_t)b * L_ + lb + r0) * C_ + c0 + c8;
            *reinterpret_cast<uint4*>(&Bs_h[r0][c8]) =
                *reinterpret_cast<const uint4*>(&Ah[g]);
            *reinterpret_cast<uint4*>(&Bs_l[r0][c8]) =
                *reinterpret_cast<const uint4*>(&Al[g]);
        }
        __syncthreads();

        short8 ah[4], al[4], bh[2], bl[2];
#pragma unroll
        for (int mt = 0; mt < 4; ++mt) {
            const int row = wm * 64 + mt * 16 + lc;
            ah[mt] = *reinterpret_cast<const short8*>(&As_h[row][quad * 8]);
            al[mt] = *reinterpret_cast<const short8*>(&As_l[row][quad * 8]);
        }
#pragma unroll
        for (int nt = 0; nt < 2; ++nt) {
            const int row = wn * 32 + nt * 16 + lc;
            bh[nt] = *reinterpret_cast<const short8*>(&Bs_h[row][quad * 8]);
            bl[nt] = *reinterpret_cast<const short8*>(&Bs_l[row][quad * 8]);
        }
#pragma unroll
        for (int mt = 0; mt < 4; ++mt)
#pragma unroll
            for (int nt = 0; nt < 2; ++nt) {
                acc[mt][nt] = __builtin_amdgcn_mfma_f32_16x16x32_bf16(ah[mt], bh[nt], acc[mt][nt], 0, 0, 0);
                acc[mt][nt] = __builtin_amdgcn_mfma_f32_16x16x32_bf16(ah[mt], bl[nt], acc[mt][nt], 0, 0, 0);
                acc[mt][nt] = __builtin_amdgcn_mfma_f32_16x16x32_bf16(al[mt], bh[nt], acc[mt][nt], 0, 0, 0);
            }
        __syncthreads();
    }

#pragma unroll
    for (int mt = 0; mt < 4; ++mt) {
#pragma unroll
        for (int r = 0; r < 4; ++r) {
            const int o = ob + wm * 64 + mt * 16 + quad * 4 + r;
            const float bi = bo[o];
#pragma unroll
            for (int nt = 0; nt < 2; ++nt) {
                const int l = lb + wn * 32 + nt * 16 + lc;
                Y[((size_t)b * C_ + o) * L_ + l] = acc[mt][nt][r] + bi;
            }
        }
    }
}

// ---------------------------------------------------------------------------
extern "C" void kernel_launch(void* const* d_in, const int* in_sizes, int n_in,
                              void* d_out, int out_size, void* d_ws, size_t ws_size,
                              hipStream_t stream)
{
    const float* x   = (const float*)d_in[0];
    const float* Wq  = (const float*)d_in[1];
    const float* bq  = (const float*)d_in[2];
    const float* Wk  = (const float*)d_in[3];
    const float* bk  = (const float*)d_in[4];
    const float* Wv  = (const float*)d_in[5];
    const float* bv  = (const float*)d_in[6];
    const float* Wo  = (const float*)d_in[7];
    const float* bo  = (const float*)d_in[8];
    const float* erk = (const float*)d_in[9];
    const float* erv = (const float*)d_in[10];

    char* ws = (char*)d_ws;
    const size_t MB = 1024u * 1024u;
    unsigned short* xT      = (unsigned short*)(ws);             // 8 MB
    unsigned short* Qb      = (unsigned short*)(ws + 8 * MB);    // 8 MB
    unsigned short* Kb      = (unsigned short*)(ws + 16 * MB);   // 8 MB
    unsigned short* Vb      = (unsigned short*)(ws + 24 * MB);   // 8 MB
    unsigned short* AOh     = (unsigned short*)(ws + 32 * MB);   // 8 MB
    unsigned short* AOl     = (unsigned short*)(ws + 40 * MB);   // 8 MB
    unsigned short* Wqkv_hi = (unsigned short*)(ws + 48 * MB);   // 1.5 MB
    unsigned short* Wo_hi   = (unsigned short*)(ws + 50 * MB);   // 0.5 MB
    unsigned short* Wo_lo   = (unsigned short*)(ws + 51 * MB);   // 0.5 MB
    float*          bqkv    = (float*)(ws + 52 * MB);            // 6 KB

    prep_kernel<<<256, 256, 0, stream>>>(Wq, Wk, Wv, Wo, bq, bk, bv,
                                         Wqkv_hi, Wo_hi, Wo_lo, bqkv);
    transpose_kernel<<<dim3(L_ / 32, C_ / 32, B_), 256, 0, stream>>>(x, xT);
    qkv_gemm_kernel<<<dim3(L_ / 128, 12, B_), 256, 0, stream>>>(
        Wqkv_hi, bqkv, xT, Qb, Kb, Vb);
    attn_kernel2<<<dim3(L_ / 64, B_ * H_), 256, 0, stream>>>(
        Qb, Kb, Vb, erk, erv, AOh, AOl);
    out_gemm_kernel<<<dim3(L_ / 64, C_ / 128, B_), 256, 0, stream>>>(
        Wo_hi, Wo_lo, bo, AOh, AOl, (float*)d_out);
}

// Round 5
// 264.877 us; speedup vs baseline: 3.1375x; 1.0116x over previous
//
#include <hip/hip_runtime.h>
#include <math.h>

#define B_  8
#define H_  8
#define C_  512
#define L_  1024
#define DH  64
#define WIN 4

typedef __attribute__((ext_vector_type(8))) short short8;
typedef __attribute__((ext_vector_type(4))) float floatx4;

__device__ __forceinline__ unsigned short f2bf(float f) {
    unsigned int u = __float_as_uint(f);
    u = u + 0x7FFFu + ((u >> 16) & 1u);     // RNE
    return (unsigned short)(u >> 16);
}
__device__ __forceinline__ float bf2f(unsigned short h) {
    return __uint_as_float(((unsigned int)h) << 16);
}

// ---------------------------------------------------------------------------
// prep: Wq/Wk/Wv -> bf16 hi (packed 3x512x512), Wo -> hi+lo, pack biases.
// ---------------------------------------------------------------------------
__global__ __launch_bounds__(256) void prep_kernel(
    const float* __restrict__ Wq, const float* __restrict__ Wk,
    const float* __restrict__ Wv, const float* __restrict__ Wo,
    const float* __restrict__ bq, const float* __restrict__ bk,
    const float* __restrict__ bv,
    unsigned short* __restrict__ Wqkv_hi,
    unsigned short* __restrict__ Wo_hi, unsigned short* __restrict__ Wo_lo,
    float* __restrict__ bqkv)
{
    const int i = blockIdx.x * 256 + threadIdx.x;   // 65536 float4 slots
    float4 v; ushort4 h;

    v = ((const float4*)Wq)[i];
    h.x = f2bf(v.x); h.y = f2bf(v.y); h.z = f2bf(v.z); h.w = f2bf(v.w);
    ((ushort4*)Wqkv_hi)[i] = h;

    v = ((const float4*)Wk)[i];
    h.x = f2bf(v.x); h.y = f2bf(v.y); h.z = f2bf(v.z); h.w = f2bf(v.w);
    ((ushort4*)Wqkv_hi)[65536 + i] = h;

    v = ((const float4*)Wv)[i];
    h.x = f2bf(v.x); h.y = f2bf(v.y); h.z = f2bf(v.z); h.w = f2bf(v.w);
    ((ushort4*)Wqkv_hi)[131072 + i] = h;

    v = ((const float4*)Wo)[i];
    h.x = f2bf(v.x); h.y = f2bf(v.y); h.z = f2bf(v.z); h.w = f2bf(v.w);
    ((ushort4*)Wo_hi)[i] = h;
    ushort4 lo;
    lo.x = f2bf(v.x - bf2f(h.x)); lo.y = f2bf(v.y - bf2f(h.y));
    lo.z = f2bf(v.z - bf2f(h.z)); lo.w = f2bf(v.w - bf2f(h.w));
    ((ushort4*)Wo_lo)[i] = lo;

    if (i < 512)       bqkv[i] = bq[i];
    else if (i < 1024) bqkv[i] = bk[i - 512];
    else if (i < 1536) bqkv[i] = bv[i - 1024];
}

// ---------------------------------------------------------------------------
// x (B,C,L) fp32 -> xT bf16 (B,L,C).  32x32 LDS transpose.
// ---------------------------------------------------------------------------
__global__ __launch_bounds__(256) void transpose_kernel(
    const float* __restrict__ x, unsigned short* __restrict__ xT)
{
    __shared__ float tile[32][33];
    const int b  = blockIdx.z;
    const int cb = blockIdx.y * 32;
    const int lb = blockIdx.x * 32;
    const int t  = threadIdx.x;
    {
        const int l = t & 31, c0 = t >> 5;
#pragma unroll
        for (int p = 0; p < 4; ++p) {
            const int c = c0 + 8 * p;
            tile[c][l] = x[((size_t)b * C_ + cb + c) * L_ + lb + l];
        }
    }
    __syncthreads();
    {
        const int c = t & 31, l0 = t >> 5;
#pragma unroll
        for (int p = 0; p < 4; ++p) {
            const int l = l0 + 8 * p;
            xT[((size_t)b * L_ + lb + l) * C_ + cb + c] = f2bf(tile[c][l]);
        }
    }
}

// ---------------------------------------------------------------------------
// Fused QKV GEMM, plain bf16.  M=1536 (3 matrices) x N=1024 x K=512.
// ---------------------------------------------------------------------------
__global__ __launch_bounds__(256) void qkv_gemm_kernel(
    const unsigned short* __restrict__ Wh, const float* __restrict__ bqkv,
    const unsigned short* __restrict__ xT,
    unsigned short* __restrict__ Qb, unsigned short* __restrict__ Kb,
    unsigned short* __restrict__ Vb)
{
    __shared__ __align__(16) unsigned short As[128][40];
    __shared__ __align__(16) unsigned short Bs[128][40];

    const int b   = blockIdx.z;
    const int oB  = blockIdx.y * 128;       // 0..1536
    const int mat = oB >> 9;                // 0=Q,1=K,2=V
    const int ob  = oB & 511;
    const int lb  = blockIdx.x * 128;
    const int t  = threadIdx.x;
    const int w = t >> 6, lane = t & 63, quad = lane >> 4, lc = lane & 15;
    const int wm = w >> 1, wn = w & 1;

    const unsigned short* Wm = Wh + (size_t)mat * C_ * C_;

    floatx4 acc[4][4];
#pragma unroll
    for (int i = 0; i < 4; ++i)
#pragma unroll
        for (int j = 0; j < 4; ++j) acc[i][j] = (floatx4)0.f;

    const int c8 = (t & 3) * 8, r0 = t >> 2;
    for (int c0 = 0; c0 < C_; c0 += 32) {
#pragma unroll
        for (int p = 0; p < 2; ++p) {
            *reinterpret_cast<uint4*>(&As[r0 + 64 * p][c8]) =
                *reinterpret_cast<const uint4*>(&Wm[(size_t)(ob + r0 + 64 * p) * C_ + c0 + c8]);
            *reinterpret_cast<uint4*>(&Bs[r0 + 64 * p][c8]) =
                *reinterpret_cast<const uint4*>(&xT[((size_t)b * L_ + lb + r0 + 64 * p) * C_ + c0 + c8]);
        }
        __syncthreads();

        short8 a[4], bb[4];
#pragma unroll
        for (int mt = 0; mt < 4; ++mt)
            a[mt] = *reinterpret_cast<const short8*>(&As[wm * 64 + mt * 16 + lc][quad * 8]);
#pragma unroll
        for (int nt = 0; nt < 4; ++nt)
            bb[nt] = *reinterpret_cast<const short8*>(&Bs[wn * 64 + nt * 16 + lc][quad * 8]);
#pragma unroll
        for (int mt = 0; mt < 4; ++mt)
#pragma unroll
            for (int nt = 0; nt < 4; ++nt)
                acc[mt][nt] = __builtin_amdgcn_mfma_f32_16x16x32_bf16(a[mt], bb[nt], acc[mt][nt], 0, 0, 0);
        __syncthreads();
    }

    const float scale = (mat == 0) ? 0.125f : 1.0f;
    unsigned short* dstQK = (mat == 0) ? Qb : Kb;
#pragma unroll
    for (int mt = 0; mt < 4; ++mt) {
#pragma unroll
        for (int r = 0; r < 4; ++r) {
            const int o  = ob + wm * 64 + mt * 16 + quad * 4 + r;
            const float bi = bqkv[mat * 512 + o];
#pragma unroll
            for (int nt = 0; nt < 4; ++nt) {
                const int l = lb + wn * 64 + nt * 16 + lc;
                const float val = (acc[mt][nt][r] + bi) * scale;
                if (mat < 2) {
                    const int hh = o >> 6, d = o & 63;
                    dstQK[(((size_t)b * H_ + hh) * L_ + l) * DH + d] = f2bf(val);
                } else {
                    Vb[((size_t)b * C_ + o) * L_ + l] = f2bf(val);
                }
            }
        }
    }
}

// ---------------------------------------------------------------------------
// Attention v3: ONE WAVE PER BLOCK (64 thr), 16 q-rows, 16 key-tiles of 64.
// grid = (64 bh, 64 row-tiles): linear id = rt*64+bh -> id%8 = bh%8, all
// blocks of one head land on one XCD (K/V per XCD = 2 MB < 4 MB L2).
// K register-prefetched one tile ahead; V hoisted to iteration top.
// Row-sums accumulated via MFMA with ones-B (lands in C/D row layout).
// No __syncthreads at all; LDS is same-wave (in-order DS pipe).
// ---------------------------------------------------------------------------
__global__ __launch_bounds__(64) void attn_kernel3(
    const unsigned short* __restrict__ Qb, const unsigned short* __restrict__ Kb,
    const unsigned short* __restrict__ Vb,
    const float* __restrict__ erel_k, const float* __restrict__ erel_v,
    unsigned short* __restrict__ AOh, unsigned short* __restrict__ AOl)
{
    __shared__ __align__(16) unsigned short Pl[16][72];
    __shared__ float rs[16][9];
    __shared__ float rv[16][9];

    const int lane = threadIdx.x;
    const int bh   = blockIdx.x;        // 0..63
    const int rt   = blockIdx.y;        // 0..63
    const int b = bh >> 3, h = bh & 7;
    const int quad = lane >> 4, lc = lane & 15;
    const int row0 = rt * 16;

    const size_t qkBase = (size_t)bh * L_ * DH;
    const size_t vBase  = ((size_t)b * C_ + h * DH) * L_;

    for (int i = lane; i < 16 * 9; i += 64) rv[i / 9][i % 9] = 0.f;

    // Q A-fragments (row = row0 + lc), reused across all 16 tiles
    short8 af[2];
#pragma unroll
    for (int kk = 0; kk < 2; ++kk)
        af[kk] = *reinterpret_cast<const short8*>(
            &Qb[qkBase + (size_t)(row0 + lc) * DH + kk * 32 + quad * 8]);

    // rel-k scores via MFMA: B[n=dr][k=d] = erk[dr][d]
    {
        floatx4 rsa = (floatx4)0.f;
        const int erow = (lc < 9) ? lc : 8;
#pragma unroll
        for (int kk = 0; kk < 2; ++kk) {
            const float* ep = erel_k + erow * 64 + kk * 32 + quad * 8;
            short8 bfr;
#pragma unroll
            for (int j = 0; j < 8; ++j) bfr[j] = (short)f2bf(ep[j]);
            rsa = __builtin_amdgcn_mfma_f32_16x16x32_bf16(af[kk], bfr, rsa, 0, 0, 0);
        }
        if (lc < 9) {
#pragma unroll
            for (int r = 0; r < 4; ++r) rs[quad * 4 + r][lc] = rsa[r];
        }
    }

    // ones B-fragment for row-sum MFMA (bf16 1.0 = 0x3F80)
    short8 ones;
#pragma unroll
    for (int j = 0; j < 8; ++j) ones[j] = (short)0x3F80;

    floatx4 acc_o[4], acc_l = (floatx4)0.f;
#pragma unroll
    for (int nt = 0; nt < 4; ++nt) acc_o[nt] = (floatx4)0.f;

    // prologue: K fragments for tile 0
    short8 kf[8];
#pragma unroll
    for (int nt = 0; nt < 4; ++nt)
#pragma unroll
        for (int kk = 0; kk < 2; ++kk)
            kf[nt * 2 + kk] = *reinterpret_cast<const short8*>(
                &Kb[qkBase + (size_t)(nt * 16 + lc) * DH + kk * 32 + quad * 8]);

    for (int jt = 0; jt < L_ / 64; ++jt) {
        const int j0 = jt * 64;

        // V fragments for this tile (consumed ~250 cyc later)
        short8 vf[8];
#pragma unroll
        for (int nt = 0; nt < 4; ++nt)
#pragma unroll
            for (int kk = 0; kk < 2; ++kk)
                vf[nt * 2 + kk] = *reinterpret_cast<const short8*>(
                    &Vb[vBase + (size_t)(nt * 16 + lc) * L_ + j0 + kk * 32 + quad * 8]);

        // S = Q K^T
        floatx4 sacc[4];
#pragma unroll
        for (int nt = 0; nt < 4; ++nt) sacc[nt] = (floatx4)0.f;
#pragma unroll
        for (int nt = 0; nt < 4; ++nt)
#pragma unroll
            for (int kk = 0; kk < 2; ++kk)
                sacc[nt] = __builtin_amdgcn_mfma_f32_16x16x32_bf16(
                    af[kk], kf[nt * 2 + kk], sacc[nt], 0, 0, 0);

        // prefetch K for jt+1 (hidden under exp + LDS + PV)
        if (jt < L_ / 64 - 1) {
            const int j0n = j0 + 64;
#pragma unroll
            for (int nt = 0; nt < 4; ++nt)
#pragma unroll
                for (int kk = 0; kk < 2; ++kk)
                    kf[nt * 2 + kk] = *reinterpret_cast<const short8*>(
                        &Kb[qkBase + (size_t)(j0n + nt * 16 + lc) * DH + kk * 32 + quad * 8]);
        }

        // windowed rel-k bias (at most 2 of 16 tiles)
        const bool nearD = (j0 <= row0 + 15 + WIN) && (j0 + 63 >= row0 - WIN);
        if (nearD) {
#pragma unroll
            for (int nt = 0; nt < 4; ++nt) {
                const int jg = j0 + nt * 16 + lc;
#pragma unroll
                for (int r = 0; r < 4; ++r) {
                    const int diff = jg - (row0 + quad * 4 + r);
                    if (diff >= -WIN && diff <= WIN)
                        sacc[nt][r] += rs[quad * 4 + r][diff + WIN];
                }
            }
        }

        // exp (no max subtraction; scores bounded ~|6|), P -> LDS bf16
#pragma unroll
        for (int nt = 0; nt < 4; ++nt)
#pragma unroll
            for (int r = 0; r < 4; ++r)
                Pl[quad * 4 + r][nt * 16 + lc] = f2bf(__expf(sacc[nt][r]));

        // rel-v prob accumulation (gated)
        if (nearD) {
            for (int idx = lane; idx < 16 * 9; idx += 64) {
                const int r16 = idx / 9, dr = idx % 9;
                const int jg = row0 + r16 + dr - WIN;
                if (jg >= j0 && jg < j0 + 64 && jg >= 0 && jg < L_)
                    rv[r16][dr] += bf2f(Pl[r16][jg - j0]);
            }
        }

        // P back as A-fragments
        short8 pf[2];
#pragma unroll
        for (int kk = 0; kk < 2; ++kk)
            pf[kk] = *reinterpret_cast<const short8*>(&Pl[lc][kk * 32 + quad * 8]);

        // row sums via MFMA (every lane ends with rowsum in acc_l[r])
#pragma unroll
        for (int kk = 0; kk < 2; ++kk)
            acc_l = __builtin_amdgcn_mfma_f32_16x16x32_bf16(pf[kk], ones, acc_l, 0, 0, 0);

        // O += P V
#pragma unroll
        for (int nt = 0; nt < 4; ++nt)
#pragma unroll
            for (int kk = 0; kk < 2; ++kk)
                acc_o[nt] = __builtin_amdgcn_mfma_f32_16x16x32_bf16(
                    pf[kk], vf[nt * 2 + kk], acc_o[nt], 0, 0, 0);
    }

    // epilogue: rel-v term, normalize, write AO hi/lo bf16 (B,L,C)
#pragma unroll
    for (int nt = 0; nt < 4; ++nt) {
        const int d = nt * 16 + lc;
#pragma unroll
        for (int r = 0; r < 4; ++r) {
            const int row = quad * 4 + r;
            float v = acc_o[nt][r];
            for (int dr = 0; dr < 9; ++dr) v += rv[row][dr] * erel_v[dr * 64 + d];
            const float outv = v / acc_l[r];
            const unsigned short hi = f2bf(outv);
            const unsigned short lo = f2bf(outv - bf2f(hi));
            const size_t idx = ((size_t)b * L_ + row0 + row) * C_ + h * 64 + d;
            AOh[idx] = hi;
            AOl[idx] = lo;
        }
    }
}

// ---------------------------------------------------------------------------
// Output projection, 3-term hi/lo split.  M=512 x N-tile 64 x K=512.
// ---------------------------------------------------------------------------
__global__ __launch_bounds__(256) void out_gemm_kernel(
    const unsigned short* __restrict__ Wh, const unsigned short* __restrict__ Wl,
    const float* __restrict__ bo,
    const unsigned short* __restrict__ Ah, const unsigned short* __restrict__ Al,
    float* __restrict__ Y)
{
    __shared__ __align__(16) unsigned short As_h[128][40];
    __shared__ __align__(16) unsigned short As_l[128][40];
    __shared__ __align__(16) unsigned short Bs_h[64][40];
    __shared__ __align__(16) unsigned short Bs_l[64][40];

    const int b  = blockIdx.z;
    const int ob = blockIdx.y * 128;
    const int lb = blockIdx.x * 64;
    const int t  = threadIdx.x;
    const int w = t >> 6, lane = t & 63, quad = lane >> 4, lc = lane & 15;
    const int wm = w >> 1, wn = w & 1;     // wave tile: 64 M x 32 N

    floatx4 acc[4][2];
#pragma unroll
    for (int i = 0; i < 4; ++i)
#pragma unroll
        for (int j = 0; j < 2; ++j) acc[i][j] = (floatx4)0.f;

    const int c8 = (t & 3) * 8, r0 = t >> 2;
    for (int c0 = 0; c0 < C_; c0 += 32) {
#pragma unroll
        for (int p = 0; p < 2; ++p) {
            *reinterpret_cast<uint4*>(&As_h[r0 + 64 * p][c8]) =
                *reinterpret_cast<const uint4*>(&Wh[(size_t)(ob + r0 + 64 * p) * C_ + c0 + c8]);
            *reinterpret_cast<uint4*>(&As_l[r0 + 64 * p][c8]) =
                *reinterpret_cast<const uint4*>(&Wl[(size_t)(ob + r0 + 64 * p) * C_ + c0 + c8]);
        }
        {
            const size_t g = ((size_t)b * L_ + lb + r0) * C_ + c0 + c8;
            *reinterpret_cast<uint4*>(&Bs_h[r0][c8]) =
                *reinterpret_cast<const uint4*>(&Ah[g]);
            *reinterpret_cast<uint4*>(&Bs_l[r0][c8]) =
                *reinterpret_cast<const uint4*>(&Al[g]);
        }
        __syncthreads();

        short8 ah[4], al[4], bh[2], bl[2];
#pragma unroll
        for (int mt = 0; mt < 4; ++mt) {
            const int row = wm * 64 + mt * 16 + lc;
            ah[mt] = *reinterpret_cast<const short8*>(&As_h[row][quad * 8]);
            al[mt] = *reinterpret_cast<const short8*>(&As_l[row][quad * 8]);
        }
#pragma unroll
        for (int nt = 0; nt < 2; ++nt) {
            const int row = wn * 32 + nt * 16 + lc;
            bh[nt] = *reinterpret_cast<const short8*>(&Bs_h[row][quad * 8]);
            bl[nt] = *reinterpret_cast<const short8*>(&Bs_l[row][quad * 8]);
        }
#pragma unroll
        for (int mt = 0; mt < 4; ++mt)
#pragma unroll
            for (int nt = 0; nt < 2; ++nt) {
                acc[mt][nt] = __builtin_amdgcn_mfma_f32_16x16x32_bf16(ah[mt], bh[nt], acc[mt][nt], 0, 0, 0);
                acc[mt][nt] = __builtin_amdgcn_mfma_f32_16x16x32_bf16(ah[mt], bl[nt], acc[mt][nt], 0, 0, 0);
                acc[mt][nt] = __builtin_amdgcn_mfma_f32_16x16x32_bf16(al[mt], bh[nt], acc[mt][nt], 0, 0, 0);
            }
        __syncthreads();
    }

#pragma unroll
    for (int mt = 0; mt < 4; ++mt) {
#pragma unroll
        for (int r = 0; r < 4; ++r) {
            const int o = ob + wm * 64 + mt * 16 + quad * 4 + r;
            const float bi = bo[o];
#pragma unroll
            for (int nt = 0; nt < 2; ++nt) {
                const int l = lb + wn * 32 + nt * 16 + lc;
                Y[((size_t)b * C_ + o) * L_ + l] = acc[mt][nt][r] + bi;
            }
        }
    }
}

// ---------------------------------------------------------------------------
extern "C" void kernel_launch(void* const* d_in, const int* in_sizes, int n_in,
                              void* d_out, int out_size, void* d_ws, size_t ws_size,
                              hipStream_t stream)
{
    const float* x   = (const float*)d_in[0];
    const float* Wq  = (const float*)d_in[1];
    const float* bq  = (const float*)d_in[2];
    const float* Wk  = (const float*)d_in[3];
    const float* bk  = (const float*)d_in[4];
    const float* Wv  = (const float*)d_in[5];
    const float* bv  = (const float*)d_in[6];
    const float* Wo  = (const float*)d_in[7];
    const float* bo  = (const float*)d_in[8];
    const float* erk = (const float*)d_in[9];
    const float* erv = (const float*)d_in[10];

    char* ws = (char*)d_ws;
    const size_t MB = 1024u * 1024u;
    unsigned short* xT      = (unsigned short*)(ws);             // 8 MB
    unsigned short* Qb      = (unsigned short*)(ws + 8 * MB);    // 8 MB
    unsigned short* Kb      = (unsigned short*)(ws + 16 * MB);   // 8 MB
    unsigned short* Vb      = (unsigned short*)(ws + 24 * MB);   // 8 MB
    unsigned short* AOh     = (unsigned short*)(ws + 32 * MB);   // 8 MB
    unsigned short* AOl     = (unsigned short*)(ws + 40 * MB);   // 8 MB
    unsigned short* Wqkv_hi = (unsigned short*)(ws + 48 * MB);   // 1.5 MB
    unsigned short* Wo_hi   = (unsigned short*)(ws + 50 * MB);   // 0.5 MB
    unsigned short* Wo_lo   = (unsigned short*)(ws + 51 * MB);   // 0.5 MB
    float*          bqkv    = (float*)(ws + 52 * MB);            // 6 KB

    prep_kernel<<<256, 256, 0, stream>>>(Wq, Wk, Wv, Wo, bq, bk, bv,
                                         Wqkv_hi, Wo_hi, Wo_lo, bqkv);
    transpose_kernel<<<dim3(L_ / 32, C_ / 32, B_), 256, 0, stream>>>(x, xT);
    qkv_gemm_kernel<<<dim3(L_ / 128, 12, B_), 256, 0, stream>>>(
        Wqkv_hi, bqkv, xT, Qb, Kb, Vb);
    attn_kernel3<<<dim3(64, 64), 64, 0, stream>>>(
        Qb, Kb, Vb, erk, erv, AOh, AOl);
    out_gemm_kernel<<<dim3(L_ / 64, C_ / 128, B_), 256, 0, stream>>>(
        Wo_hi, Wo_lo, bo, AOh, AOl, (float*)d_out);
}

// Round 6
// 215.148 us; speedup vs baseline: 3.8627x; 1.2311x over previous
//
#include <hip/hip_runtime.h>
#include <math.h>

#define B_  8
#define H_  8
#define C_  512
#define L_  1024
#define DH  64
#define WIN 4

typedef __attribute__((ext_vector_type(8))) short short8;
typedef __attribute__((ext_vector_type(4))) float floatx4;

__device__ __forceinline__ unsigned short f2bf(float f) {
    unsigned int u = __float_as_uint(f);
    u = u + 0x7FFFu + ((u >> 16) & 1u);     // RNE
    return (unsigned short)(u >> 16);
}
__device__ __forceinline__ float bf2f(unsigned short h) {
    return __uint_as_float(((unsigned int)h) << 16);
}

// ---------------------------------------------------------------------------
// prep: Wq/Wk/Wv -> bf16 hi (packed 3x512x512), Wo -> hi+lo, pack biases.
// ---------------------------------------------------------------------------
__global__ __launch_bounds__(256) void prep_kernel(
    const float* __restrict__ Wq, const float* __restrict__ Wk,
    const float* __restrict__ Wv, const float* __restrict__ Wo,
    const float* __restrict__ bq, const float* __restrict__ bk,
    const float* __restrict__ bv,
    unsigned short* __restrict__ Wqkv_hi,
    unsigned short* __restrict__ Wo_hi, unsigned short* __restrict__ Wo_lo,
    float* __restrict__ bqkv)
{
    const int i = blockIdx.x * 256 + threadIdx.x;   // 65536 float4 slots
    float4 v; ushort4 h;

    v = ((const float4*)Wq)[i];
    h.x = f2bf(v.x); h.y = f2bf(v.y); h.z = f2bf(v.z); h.w = f2bf(v.w);
    ((ushort4*)Wqkv_hi)[i] = h;

    v = ((const float4*)Wk)[i];
    h.x = f2bf(v.x); h.y = f2bf(v.y); h.z = f2bf(v.z); h.w = f2bf(v.w);
    ((ushort4*)Wqkv_hi)[65536 + i] = h;

    v = ((const float4*)Wv)[i];
    h.x = f2bf(v.x); h.y = f2bf(v.y); h.z = f2bf(v.z); h.w = f2bf(v.w);
    ((ushort4*)Wqkv_hi)[131072 + i] = h;

    v = ((const float4*)Wo)[i];
    h.x = f2bf(v.x); h.y = f2bf(v.y); h.z = f2bf(v.z); h.w = f2bf(v.w);
    ((ushort4*)Wo_hi)[i] = h;
    ushort4 lo;
    lo.x = f2bf(v.x - bf2f(h.x)); lo.y = f2bf(v.y - bf2f(h.y));
    lo.z = f2bf(v.z - bf2f(h.z)); lo.w = f2bf(v.w - bf2f(h.w));
    ((ushort4*)Wo_lo)[i] = lo;

    if (i < 512)       bqkv[i] = bq[i];
    else if (i < 1024) bqkv[i] = bk[i - 512];
    else if (i < 1536) bqkv[i] = bv[i - 1024];
}

// ---------------------------------------------------------------------------
// x (B,C,L) fp32 -> xT bf16 (B,L,C).  32x32 LDS transpose.
// ---------------------------------------------------------------------------
__global__ __launch_bounds__(256) void transpose_kernel(
    const float* __restrict__ x, unsigned short* __restrict__ xT)
{
    __shared__ float tile[32][33];
    const int b  = blockIdx.z;
    const int cb = blockIdx.y * 32;
    const int lb = blockIdx.x * 32;
    const int t  = threadIdx.x;
    {
        const int l = t & 31, c0 = t >> 5;
#pragma unroll
        for (int p = 0; p < 4; ++p) {
            const int c = c0 + 8 * p;
            tile[c][l] = x[((size_t)b * C_ + cb + c) * L_ + lb + l];
        }
    }
    __syncthreads();
    {
        const int c = t & 31, l0 = t >> 5;
#pragma unroll
        for (int p = 0; p < 4; ++p) {
            const int l = l0 + 8 * p;
            xT[((size_t)b * L_ + lb + l) * C_ + cb + c] = f2bf(tile[c][l]);
        }
    }
}

// ---------------------------------------------------------------------------
// Fused QKV GEMM, plain bf16.  M=1536 (3 matrices) x N=1024 x K=512.
// ---------------------------------------------------------------------------
__global__ __launch_bounds__(256) void qkv_gemm_kernel(
    const unsigned short* __restrict__ Wh, const float* __restrict__ bqkv,
    const unsigned short* __restrict__ xT,
    unsigned short* __restrict__ Qb, unsigned short* __restrict__ Kb,
    unsigned short* __restrict__ Vb)
{
    __shared__ __align__(16) unsigned short As[128][40];
    __shared__ __align__(16) unsigned short Bs[128][40];

    const int b   = blockIdx.z;
    const int oB  = blockIdx.y * 128;       // 0..1536
    const int mat = oB >> 9;                // 0=Q,1=K,2=V
    const int ob  = oB & 511;
    const int lb  = blockIdx.x * 128;
    const int t  = threadIdx.x;
    const int w = t >> 6, lane = t & 63, quad = lane >> 4, lc = lane & 15;
    const int wm = w >> 1, wn = w & 1;

    const unsigned short* Wm = Wh + (size_t)mat * C_ * C_;

    floatx4 acc[4][4];
#pragma unroll
    for (int i = 0; i < 4; ++i)
#pragma unroll
        for (int j = 0; j < 4; ++j) acc[i][j] = (floatx4)0.f;

    const int c8 = (t & 3) * 8, r0 = t >> 2;
    for (int c0 = 0; c0 < C_; c0 += 32) {
#pragma unroll
        for (int p = 0; p < 2; ++p) {
            *reinterpret_cast<uint4*>(&As[r0 + 64 * p][c8]) =
                *reinterpret_cast<const uint4*>(&Wm[(size_t)(ob + r0 + 64 * p) * C_ + c0 + c8]);
            *reinterpret_cast<uint4*>(&Bs[r0 + 64 * p][c8]) =
                *reinterpret_cast<const uint4*>(&xT[((size_t)b * L_ + lb + r0 + 64 * p) * C_ + c0 + c8]);
        }
        __syncthreads();

        short8 a[4], bb[4];
#pragma unroll
        for (int mt = 0; mt < 4; ++mt)
            a[mt] = *reinterpret_cast<const short8*>(&As[wm * 64 + mt * 16 + lc][quad * 8]);
#pragma unroll
        for (int nt = 0; nt < 4; ++nt)
            bb[nt] = *reinterpret_cast<const short8*>(&Bs[wn * 64 + nt * 16 + lc][quad * 8]);
#pragma unroll
        for (int mt = 0; mt < 4; ++mt)
#pragma unroll
            for (int nt = 0; nt < 4; ++nt)
                acc[mt][nt] = __builtin_amdgcn_mfma_f32_16x16x32_bf16(a[mt], bb[nt], acc[mt][nt], 0, 0, 0);
        __syncthreads();
    }

    const float scale = (mat == 0) ? 0.125f : 1.0f;
    unsigned short* dstQK = (mat == 0) ? Qb : Kb;
#pragma unroll
    for (int mt = 0; mt < 4; ++mt) {
#pragma unroll
        for (int r = 0; r < 4; ++r) {
            const int o  = ob + wm * 64 + mt * 16 + quad * 4 + r;
            const float bi = bqkv[mat * 512 + o];
#pragma unroll
            for (int nt = 0; nt < 4; ++nt) {
                const int l = lb + wn * 64 + nt * 16 + lc;
                const float val = (acc[mt][nt][r] + bi) * scale;
                if (mat < 2) {
                    const int hh = o >> 6, d = o & 63;
                    dstQK[(((size_t)b * H_ + hh) * L_ + l) * DH + d] = f2bf(val);
                } else {
                    Vb[((size_t)b * C_ + o) * L_ + l] = f2bf(val);
                }
            }
        }
    }
}

// ---------------------------------------------------------------------------
// Attention v4: L2-traffic-minimized.
// 512 blocks (bh 64 x rt 8), 256 thr / 4 waves, 128 q-rows per block,
// 32 q-rows per wave (2 row-groups reuse each K/V fragment read).
// K/V tiles double-buffered in LDS (read from L2 ONCE per block: 256 MB
// total vs 1 GB for per-wave global loads — the R5 bottleneck).
// One barrier per key-tile; register-mediated prefetch of the next tile.
// No-max softmax (scores ~N(0,1), |s|max ~ 6sigma; exp safe in fp32).
// ---------------------------------------------------------------------------
__global__ __launch_bounds__(256, 2) void attn_kernel4(
    const unsigned short* __restrict__ Qb, const unsigned short* __restrict__ Kb,
    const unsigned short* __restrict__ Vb,
    const float* __restrict__ erel_k, const float* __restrict__ erel_v,
    unsigned short* __restrict__ AOh, unsigned short* __restrict__ AOl)
{
    __shared__ __align__(16) unsigned short kst[2][64][72];  // [buf][j][d]
    __shared__ __align__(16) unsigned short vst[2][64][72];  // [buf][d][j]
    __shared__ __align__(16) unsigned short Pl[4][32][72];   // per-wave P
    __shared__ float rs[128][9];
    __shared__ float rv[128][9];

    const int t    = threadIdx.x;
    const int bh   = blockIdx.x;        // 0..63  (id%8 == h -> XCD locality)
    const int rt   = blockIdx.y;        // 0..7
    const int b = bh >> 3, h = bh & 7;
    const int w = t >> 6, lane = t & 63, quad = lane >> 4, lc = lane & 15;
    const int row0 = rt * 128;          // block's first q-row
    const int rowW = row0 + w * 32;     // wave's first q-row

    const size_t qkBase = (size_t)bh * L_ * DH;
    const size_t vBase  = ((size_t)b * C_ + h * DH) * L_;

    // init rv (wave-private rows)
    for (int i = lane; i < 32 * 9; i += 64) rv[w * 32 + i / 9][i % 9] = 0.f;

    // Q A-fragments: rg row-groups of 16 rows
    short8 af[2][2];
#pragma unroll
    for (int rg = 0; rg < 2; ++rg)
#pragma unroll
        for (int kk = 0; kk < 2; ++kk)
            af[rg][kk] = *reinterpret_cast<const short8*>(
                &Qb[qkBase + (size_t)(rowW + rg * 16 + lc) * DH + kk * 32 + quad * 8]);

    // rel-k scores via MFMA: B[n=dr][k=d] = erk[dr][d]
#pragma unroll
    for (int rg = 0; rg < 2; ++rg) {
        floatx4 rsa = (floatx4)0.f;
        const int erow = (lc < 9) ? lc : 8;
#pragma unroll
        for (int kk = 0; kk < 2; ++kk) {
            const float* ep = erel_k + erow * 64 + kk * 32 + quad * 8;
            short8 bfr;
#pragma unroll
            for (int j = 0; j < 8; ++j) bfr[j] = (short)f2bf(ep[j]);
            rsa = __builtin_amdgcn_mfma_f32_16x16x32_bf16(af[rg][kk], bfr, rsa, 0, 0, 0);
        }
        if (lc < 9) {
#pragma unroll
            for (int r = 0; r < 4; ++r)
                rs[w * 32 + rg * 16 + quad * 4 + r][lc] = rsa[r];
        }
    }

    // stage tile 0 into buffer 0 (contiguous row streams)
    {
        const int jr = t >> 3, jc = (t & 7) * 8;
#pragma unroll
        for (int p = 0; p < 2; ++p) {
            *reinterpret_cast<uint4*>(&kst[0][jr + 32 * p][jc]) =
                *reinterpret_cast<const uint4*>(&Kb[qkBase + (size_t)(jr + 32 * p) * DH + jc]);
            *reinterpret_cast<uint4*>(&vst[0][jr + 32 * p][jc]) =
                *reinterpret_cast<const uint4*>(&Vb[vBase + (size_t)(jr + 32 * p) * L_ + jc]);
        }
    }
    __syncthreads();

    // ones B-fragment for row-sum MFMA (bf16 1.0 = 0x3F80)
    short8 ones;
#pragma unroll
    for (int j = 0; j < 8; ++j) ones[j] = (short)0x3F80;

    floatx4 acc_o[2][4], acc_l[2];
#pragma unroll
    for (int rg = 0; rg < 2; ++rg) {
        acc_l[rg] = (floatx4)0.f;
#pragma unroll
        for (int nt = 0; nt < 4; ++nt) acc_o[rg][nt] = (floatx4)0.f;
    }

    const int jr = t >> 3, jc = (t & 7) * 8;

    for (int jt = 0; jt < L_ / 64; ++jt) {
        const int j0  = jt * 64;
        const int cur = jt & 1;

        // prefetch next tile into registers (latency hidden under compute)
        uint4 pk[2], pv[2];
        if (jt < L_ / 64 - 1) {
            const int j0n = j0 + 64;
#pragma unroll
            for (int p = 0; p < 2; ++p) {
                pk[p] = *reinterpret_cast<const uint4*>(
                    &Kb[qkBase + (size_t)(j0n + jr + 32 * p) * DH + jc]);
                pv[p] = *reinterpret_cast<const uint4*>(
                    &Vb[vBase + (size_t)(jr + 32 * p) * L_ + j0n + jc]);
            }
        }

        // K fragments from LDS (shared by both row-groups)
        short8 kf[4][2];
#pragma unroll
        for (int nt = 0; nt < 4; ++nt)
#pragma unroll
            for (int kk = 0; kk < 2; ++kk)
                kf[nt][kk] = *reinterpret_cast<const short8*>(
                    &kst[cur][nt * 16 + lc][kk * 32 + quad * 8]);

#pragma unroll
        for (int rg = 0; rg < 2; ++rg) {
            const int rowWg = rowW + rg * 16;

            // S = Q K^T
            floatx4 sacc[4];
#pragma unroll
            for (int nt = 0; nt < 4; ++nt) sacc[nt] = (floatx4)0.f;
#pragma unroll
            for (int nt = 0; nt < 4; ++nt)
#pragma unroll
                for (int kk = 0; kk < 2; ++kk)
                    sacc[nt] = __builtin_amdgcn_mfma_f32_16x16x32_bf16(
                        af[rg][kk], kf[nt][kk], sacc[nt], 0, 0, 0);

            // windowed rel-k bias (near-diagonal tiles only)
            const bool nearD = (j0 <= rowWg + 15 + WIN) && (j0 + 63 >= rowWg - WIN);
            if (nearD) {
#pragma unroll
                for (int nt = 0; nt < 4; ++nt) {
                    const int jg = j0 + nt * 16 + lc;
#pragma unroll
                    for (int r = 0; r < 4; ++r) {
                        const int diff = jg - (rowWg + quad * 4 + r);
                        if (diff >= -WIN && diff <= WIN)
                            sacc[nt][r] += rs[w * 32 + rg * 16 + quad * 4 + r][diff + WIN];
                    }
                }
            }

            // exp, P -> LDS bf16
#pragma unroll
            for (int nt = 0; nt < 4; ++nt)
#pragma unroll
                for (int r = 0; r < 4; ++r)
                    Pl[w][rg * 16 + quad * 4 + r][nt * 16 + lc] = f2bf(__expf(sacc[nt][r]));

            // rel-v prob accumulation (gated; wave-private rows)
            if (nearD) {
                for (int idx = lane; idx < 16 * 9; idx += 64) {
                    const int r16 = idx / 9, dr = idx % 9;
                    const int rloc = w * 32 + rg * 16 + r16;
                    const int jg = row0 + rloc + dr - WIN;
                    if (jg >= j0 && jg < j0 + 64 && jg >= 0 && jg < L_)
                        rv[rloc][dr] += bf2f(Pl[w][rg * 16 + r16][jg - j0]);
                }
            }

            // P back as A-fragments
            short8 pf[2];
#pragma unroll
            for (int kk = 0; kk < 2; ++kk)
                pf[kk] = *reinterpret_cast<const short8*>(
                    &Pl[w][rg * 16 + lc][kk * 32 + quad * 8]);

            // row sums via MFMA
#pragma unroll
            for (int kk = 0; kk < 2; ++kk)
                acc_l[rg] = __builtin_amdgcn_mfma_f32_16x16x32_bf16(
                    pf[kk], ones, acc_l[rg], 0, 0, 0);

            // O += P V   (V fragments from LDS)
#pragma unroll
            for (int nt = 0; nt < 4; ++nt)
#pragma unroll
                for (int kk = 0; kk < 2; ++kk) {
                    const short8 vf = *reinterpret_cast<const short8*>(
                        &vst[cur][nt * 16 + lc][kk * 32 + quad * 8]);
                    acc_o[rg][nt] = __builtin_amdgcn_mfma_f32_16x16x32_bf16(
                        pf[kk], vf, acc_o[rg][nt], 0, 0, 0);
                }
        }

        // write prefetched tile into the other buffer, then sync
        if (jt < L_ / 64 - 1) {
#pragma unroll
            for (int p = 0; p < 2; ++p) {
                *reinterpret_cast<uint4*>(&kst[1 - cur][jr + 32 * p][jc]) = pk[p];
                *reinterpret_cast<uint4*>(&vst[1 - cur][jr + 32 * p][jc]) = pv[p];
            }
        }
        __syncthreads();
    }

    // epilogue: rel-v term, normalize, write AO hi/lo bf16 (B,L,C)
#pragma unroll
    for (int nt = 0; nt < 4; ++nt) {
        const int d = nt * 16 + lc;
        float ev[9];
#pragma unroll
        for (int dr = 0; dr < 9; ++dr) ev[dr] = erel_v[dr * 64 + d];
#pragma unroll
        for (int rg = 0; rg < 2; ++rg) {
#pragma unroll
            for (int r = 0; r < 4; ++r) {
                const int rloc = w * 32 + rg * 16 + quad * 4 + r;
                float v = acc_o[rg][nt][r];
#pragma unroll
                for (int dr = 0; dr < 9; ++dr) v += rv[rloc][dr] * ev[dr];
                const float outv = v / acc_l[rg][r];
                const unsigned short hi = f2bf(outv);
                const unsigned short lo = f2bf(outv - bf2f(hi));
                const size_t idx = ((size_t)b * L_ + row0 + rloc) * C_ + h * 64 + d;
                AOh[idx] = hi;
                AOl[idx] = lo;
            }
        }
    }
}

// ---------------------------------------------------------------------------
// Output projection, 3-term hi/lo split.  M=512 x N-tile 64 x K=512.
// ---------------------------------------------------------------------------
__global__ __launch_bounds__(256) void out_gemm_kernel(
    const unsigned short* __restrict__ Wh, const unsigned short* __restrict__ Wl,
    const float* __restrict__ bo,
    const unsigned short* __restrict__ Ah, const unsigned short* __restrict__ Al,
    float* __restrict__ Y)
{
    __shared__ __align__(16) unsigned short As_h[128][40];
    __shared__ __align__(16) unsigned short As_l[128][40];
    __shared__ __align__(16) unsigned short Bs_h[64][40];
    __shared__ __align__(16) unsigned short Bs_l[64][40];

    const int b  = blockIdx.z;
    const int ob = blockIdx.y * 128;
    const int lb = blockIdx.x * 64;
    const int t  = threadIdx.x;
    const int w = t >> 6, lane = t & 63, quad = lane >> 4, lc = lane & 15;
    const int wm = w >> 1, wn = w & 1;     // wave tile: 64 M x 32 N

    floatx4 acc[4][2];
#pragma unroll
    for (int i = 0; i < 4; ++i)
#pragma unroll
        for (int j = 0; j < 2; ++j) acc[i][j] = (floatx4)0.f;

    const int c8 = (t & 3) * 8, r0 = t >> 2;
    for (int c0 = 0; c0 < C_; c0 += 32) {
#pragma unroll
        for (int p = 0; p < 2; ++p) {
            *reinterpret_cast<uint4*>(&As_h[r0 + 64 * p][c8]) =
                *reinterpret_cast<const uint4*>(&Wh[(size_t)(ob + r0 + 64 * p) * C_ + c0 + c8]);
            *reinterpret_cast<uint4*>(&As_l[r0 + 64 * p][c8]) =
                *reinterpret_cast<const uint4*>(&Wl[(size_t)(ob + r0 + 64 * p) * C_ + c0 + c8]);
        }
        {
            const size_t g = ((size_t)b * L_ + lb + r0) * C_ + c0 + c8;
            *reinterpret_cast<uint4*>(&Bs_h[r0][c8]) =
                *reinterpret_cast<const uint4*>(&Ah[g]);
            *reinterpret_cast<uint4*>(&Bs_l[r0][c8]) =
                *reinterpret_cast<const uint4*>(&Al[g]);
        }
        __syncthreads();

        short8 ah[4], al[4], bhf[2], blf[2];
#pragma unroll
        for (int mt = 0; mt < 4; ++mt) {
            const int row = wm * 64 + mt * 16 + lc;
            ah[mt] = *reinterpret_cast<const short8*>(&As_h[row][quad * 8]);
            al[mt] = *reinterpret_cast<const short8*>(&As_l[row][quad * 8]);
        }
#pragma unroll
        for (int nt = 0; nt < 2; ++nt) {
            const int row = wn * 32 + nt * 16 + lc;
            bhf[nt] = *reinterpret_cast<const short8*>(&Bs_h[row][quad * 8]);
            blf[nt] = *reinterpret_cast<const short8*>(&Bs_l[row][quad * 8]);
        }
#pragma unroll
        for (int mt = 0; mt < 4; ++mt)
#pragma unroll
            for (int nt = 0; nt < 2; ++nt) {
                acc[mt][nt] = __builtin_amdgcn_mfma_f32_16x16x32_bf16(ah[mt], bhf[nt], acc[mt][nt], 0, 0, 0);
                acc[mt][nt] = __builtin_amdgcn_mfma_f32_16x16x32_bf16(ah[mt], blf[nt], acc[mt][nt], 0, 0, 0);
                acc[mt][nt] = __builtin_amdgcn_mfma_f32_16x16x32_bf16(al[mt], bhf[nt], acc[mt][nt], 0, 0, 0);
            }
        __syncthreads();
    }

#pragma unroll
    for (int mt = 0; mt < 4; ++mt) {
#pragma unroll
        for (int r = 0; r < 4; ++r) {
            const int o = ob + wm * 64 + mt * 16 + quad * 4 + r;
            const float bi = bo[o];
#pragma unroll
            for (int nt = 0; nt < 2; ++nt) {
                const int l = lb + wn * 32 + nt * 16 + lc;
                Y[((size_t)b * C_ + o) * L_ + l] = acc[mt][nt][r] + bi;
            }
        }
    }
}

// ---------------------------------------------------------------------------
extern "C" void kernel_launch(void* const* d_in, const int* in_sizes, int n_in,
                              void* d_out, int out_size, void* d_ws, size_t ws_size,
                              hipStream_t stream)
{
    const float* x   = (const float*)d_in[0];
    const float* Wq  = (const float*)d_in[1];
    const float* bq  = (const float*)d_in[2];
    const float* Wk  = (const float*)d_in[3];
    const float* bk  = (const float*)d_in[4];
    const float* Wv  = (const float*)d_in[5];
    const float* bv  = (const float*)d_in[6];
    const float* Wo  = (const float*)d_in[7];
    const float* bo  = (const float*)d_in[8];
    const float* erk = (const float*)d_in[9];
    const float* erv = (const float*)d_in[10];

    char* ws = (char*)d_ws;
    const size_t MB = 1024u * 1024u;
    unsigned short* xT      = (unsigned short*)(ws);             // 8 MB
    unsigned short* Qb      = (unsigned short*)(ws + 8 * MB);    // 8 MB
    unsigned short* Kb      = (unsigned short*)(ws + 16 * MB);   // 8 MB
    unsigned short* Vb      = (unsigned short*)(ws + 24 * MB);   // 8 MB
    unsigned short* AOh     = (unsigned short*)(ws + 32 * MB);   // 8 MB
    unsigned short* AOl     = (unsigned short*)(ws + 40 * MB);   // 8 MB
    unsigned short* Wqkv_hi = (unsigned short*)(ws + 48 * MB);   // 1.5 MB
    unsigned short* Wo_hi   = (unsigned short*)(ws + 50 * MB);   // 0.5 MB
    unsigned short* Wo_lo   = (unsigned short*)(ws + 51 * MB);   // 0.5 MB
    float*          bqkv    = (float*)(ws + 52 * MB);            // 6 KB

    prep_kernel<<<256, 256, 0, stream>>>(Wq, Wk, Wv, Wo, bq, bk, bv,
                                         Wqkv_hi, Wo_hi, Wo_lo, bqkv);
    transpose_kernel<<<dim3(L_ / 32, C_ / 32, B_), 256, 0, stream>>>(x, xT);
    qkv_gemm_kernel<<<dim3(L_ / 128, 12, B_), 256, 0, stream>>>(
        Wqkv_hi, bqkv, xT, Qb, Kb, Vb);
    attn_kernel4<<<dim3(64, 8), 256, 0, stream>>>(
        Qb, Kb, Vb, erk, erv, AOh, AOl);
    out_gemm_kernel<<<dim3(L_ / 64, C_ / 128, B_), 256, 0, stream>>>(
        Wo_hi, Wo_lo, bo, AOh, AOl, (float*)d_out);
}